// Round 11
// baseline (1626.166 us; speedup 1.0000x reference)
//
#include <hip/hip_runtime.h>
#include <cstdint>
#include <cstddef>

#define NB 4
#define NS 4096
#define ND 2048
#define NH 16
#define NHD 128
#define NT 1024
#define NF 8192

typedef __bf16 bf16;
typedef __bf16 bf16x8 __attribute__((ext_vector_type(8)));
typedef __bf16 bf16x4 __attribute__((ext_vector_type(4)));
typedef float  f32x4  __attribute__((ext_vector_type(4)));

typedef const __attribute__((address_space(1))) void* gptr_t;
typedef __attribute__((address_space(3))) void* lptr_t;

__device__ __forceinline__ float wave_sum(float v) {
#pragma unroll
    for (int off = 32; off > 0; off >>= 1) v += __shfl_xor(v, off);
    return v;
}
__device__ __forceinline__ float wave_max(float v) {
#pragma unroll
    for (int off = 32; off > 0; off >>= 1) v = fmaxf(v, __shfl_xor(v, off));
    return v;
}

// ---------------------------------------------------------------------------
// Router: logits[row] = dot(x[row,:], w_router)   (row = b*NS+s)
// ---------------------------------------------------------------------------
__global__ __launch_bounds__(256) void router_k(const float* __restrict__ x,
                                                const float* __restrict__ wr,
                                                float* __restrict__ logits) {
    __shared__ float r4[4];
    long long row = blockIdx.x;
    const float4* xr = (const float4*)(x + row * ND);
    const float4* w4 = (const float4*)wr;
    float p = 0.f;
    for (int i = threadIdx.x; i < ND / 4; i += 256) {
        float4 a = xr[i], b = w4[i];
        p += a.x * b.x + a.y * b.y + a.z * b.z + a.w * b.w;
    }
    p = wave_sum(p);
    if ((threadIdx.x & 63) == 0) r4[threadIdx.x >> 6] = p;
    __syncthreads();
    if (threadIdx.x == 0) logits[row] = r4[0] + r4[1] + r4[2] + r4[3];
}

// ---------------------------------------------------------------------------
// Top-K (exact, matches jax.lax.top_k tie-break) + index sort + router softmax.
// ---------------------------------------------------------------------------
__global__ __launch_bounds__(1024) void topk_k(const float* __restrict__ logits,
                                               int* __restrict__ sel,
                                               float* __restrict__ rw) {
    __shared__ unsigned long long keys[NS];   // 32 KB
    __shared__ float r16[16];
    __shared__ float bmax, bsum;
    const int bb = blockIdx.x;
    const int tid = threadIdx.x;
    const float* lg = logits + (long long)bb * NS;

    for (int i = tid; i < NS; i += 1024) {
        unsigned u = __float_as_uint(lg[i]);
        u = (u & 0x80000000u) ? ~u : (u | 0x80000000u);   // order-preserving map
        keys[i] = ((unsigned long long)u << 32) | (unsigned)(NS - 1 - i);
    }
    __syncthreads();
    for (int k = 2; k <= NS; k <<= 1) {
        for (int j = k >> 1; j > 0; j >>= 1) {
            for (int i = tid; i < NS; i += 1024) {
                int ixj = i ^ j;
                if (ixj > i) {
                    unsigned long long a = keys[i], c = keys[ixj];
                    bool up = ((i & k) == 0);
                    if (up ? (a < c) : (a > c)) { keys[i] = c; keys[ixj] = a; }
                }
            }
            __syncthreads();
        }
    }
    unsigned long long a0 = keys[tid];
    __syncthreads();
    {
        unsigned idx_ = NS - 1 - (unsigned)(a0 & 0xFFFFFFFFu);
        unsigned uval = (unsigned)(a0 >> 32);
        keys[tid] = ((unsigned long long)idx_ << 32) | uval;
    }
    __syncthreads();
    for (int k = 2; k <= NT; k <<= 1) {
        for (int j = k >> 1; j > 0; j >>= 1) {
            int i = tid, ixj = i ^ j;
            if (i < NT && ixj > i) {
                unsigned long long a = keys[i], c = keys[ixj];
                bool up = ((i & k) == 0);
                if (up ? (a > c) : (a < c)) { keys[i] = c; keys[ixj] = a; }
            }
            __syncthreads();
        }
    }
    unsigned long long kk = keys[tid];
    int si = (int)(kk >> 32);
    unsigned u = (unsigned)(kk & 0xFFFFFFFFu);
    u = (u & 0x80000000u) ? (u ^ 0x80000000u) : ~u;
    float val = __uint_as_float(u);

    const int wid = tid >> 6, lane = tid & 63;
    float mx = wave_max(val);
    if (lane == 0) r16[wid] = mx;
    __syncthreads();
    if (tid == 0) {
        float m = r16[0];
        for (int i = 1; i < 16; i++) m = fmaxf(m, r16[i]);
        bmax = m;
    }
    __syncthreads();
    float e = __expf(val - bmax);
    float s = wave_sum(e);
    if (lane == 0) r16[wid] = s;
    __syncthreads();
    if (tid == 0) {
        float t = 0.f;
        for (int i = 0; i < 16; i++) t += r16[i];
        bsum = t;
    }
    __syncthreads();
    sel[bb * NT + tid] = si;
    rw[bb * NT + tid] = e / bsum;
}

// ---------------------------------------------------------------------------
// Gather: xf[b,j,:] = x[b, sel[b,j], :]   (float4)
// ---------------------------------------------------------------------------
__global__ __launch_bounds__(256) void gather_k(const float* __restrict__ x,
                                                const int* __restrict__ sel,
                                                float* __restrict__ xf) {
    int gid = blockIdx.x * 256 + threadIdx.x;
    int col = gid & (ND / 4 - 1);
    int row = gid >> 9;
    int bb = row >> 10;
    int s = sel[row];
    ((float4*)xf)[gid] = ((const float4*)x)[((long long)bb * NS + s) * (ND / 4) + col];
}

// ---------------------------------------------------------------------------
// RMSNorm row kernel: out = bf16(x * rsqrt(mean(x^2)+eps) * g)
// ---------------------------------------------------------------------------
__global__ __launch_bounds__(256) void rmsnorm_k(const float* __restrict__ x,
                                                 const float* __restrict__ g,
                                                 bf16* __restrict__ out) {
    __shared__ float r4[4];
    __shared__ float scl;
    long long row = blockIdx.x;
    const float4* xr = (const float4*)(x + row * ND);
    int i0 = threadIdx.x, i1 = threadIdx.x + 256;
    float4 a = xr[i0], b = xr[i1];
    float ss = a.x * a.x + a.y * a.y + a.z * a.z + a.w * a.w +
               b.x * b.x + b.y * b.y + b.z * b.z + b.w * b.w;
    ss = wave_sum(ss);
    if ((threadIdx.x & 63) == 0) r4[threadIdx.x >> 6] = ss;
    __syncthreads();
    if (threadIdx.x == 0)
        scl = rsqrtf((r4[0] + r4[1] + r4[2] + r4[3]) * (1.0f / ND) + 1e-6f);
    __syncthreads();
    float s = scl;
    const float4* g4 = (const float4*)g;
    float4 ga = g4[i0], gb = g4[i1];
    bf16x4 o0, o1;
    o0[0] = (bf16)(a.x * s * ga.x); o0[1] = (bf16)(a.y * s * ga.y);
    o0[2] = (bf16)(a.z * s * ga.z); o0[3] = (bf16)(a.w * s * ga.w);
    o1[0] = (bf16)(b.x * s * gb.x); o1[1] = (bf16)(b.y * s * gb.y);
    o1[2] = (bf16)(b.z * s * gb.z); o1[3] = (bf16)(b.w * s * gb.w);
    *(bf16x4*)(out + row * ND + i0 * 4) = o0;
    *(bf16x4*)(out + row * ND + i1 * 4) = o1;
}

// ---------------------------------------------------------------------------
// Transpose + fp32->bf16 (generic): out[c][r] = in[r][c]; in is R x C.
// ---------------------------------------------------------------------------
__global__ __launch_bounds__(256) void transpose_to_bf16(const float* __restrict__ in,
                                                         bf16* __restrict__ out,
                                                         int R, int C) {
    __shared__ float tile[32][33];
    int bx = blockIdx.x * 32;   // col
    int by = blockIdx.y * 32;   // row
    int tx = threadIdx.x & 31;
    int ty = threadIdx.x >> 5;   // 0..7
#pragma unroll
    for (int i = 0; i < 4; i++)
        tile[ty + 8 * i][tx] = in[(long long)(by + ty + 8 * i) * C + bx + tx];
    __syncthreads();
#pragma unroll
    for (int i = 0; i < 4; i++)
        out[(long long)(bx + ty + 8 * i) * R + by + tx] = (bf16)tile[tx][ty + 8 * i];
}

// ---------------------------------------------------------------------------
// Merged transpose: z picks among 4 ND x ND sources (wq,wk,wv -> wqkv_t; wo).
// ---------------------------------------------------------------------------
__global__ __launch_bounds__(256) void transpose4_nd(const float* __restrict__ s0,
                                                     const float* __restrict__ s1,
                                                     const float* __restrict__ s2,
                                                     const float* __restrict__ s3,
                                                     bf16* __restrict__ d_wqkv,
                                                     bf16* __restrict__ d_wo) {
    __shared__ float tile[32][33];
    const int z = blockIdx.z;
    const float* in = (z == 0) ? s0 : (z == 1) ? s1 : (z == 2) ? s2 : s3;
    bf16* out = (z < 3) ? (d_wqkv + (size_t)z * ND * ND) : d_wo;
    int bx = blockIdx.x * 32;
    int by = blockIdx.y * 32;
    int tx = threadIdx.x & 31;
    int ty = threadIdx.x >> 5;
#pragma unroll
    for (int i = 0; i < 4; i++)
        tile[ty + 8 * i][tx] = in[(long long)(by + ty + 8 * i) * ND + bx + tx];
    __syncthreads();
#pragma unroll
    for (int i = 0; i < 4; i++)
        out[(long long)(bx + ty + 8 * i) * ND + by + tx] = (bf16)tile[tx][ty + 8 * i];
}

// ---------------------------------------------------------------------------
// Merged transpose: z picks among 2 ND x NF sources (w1 -> w1_t, w3 -> w3_t).
// ---------------------------------------------------------------------------
__global__ __launch_bounds__(256) void transpose2_ff(const float* __restrict__ s0,
                                                     const float* __restrict__ s1,
                                                     bf16* __restrict__ dst) {
    __shared__ float tile[32][33];
    const int z = blockIdx.z;
    const float* in = z ? s1 : s0;
    bf16* out = dst + (size_t)z * ND * NF;
    int bx = blockIdx.x * 32;   // col in NF
    int by = blockIdx.y * 32;   // row in ND
    int tx = threadIdx.x & 31;
    int ty = threadIdx.x >> 5;
#pragma unroll
    for (int i = 0; i < 4; i++)
        tile[ty + 8 * i][tx] = in[(long long)(by + ty + 8 * i) * NF + bx + tx];
    __syncthreads();
#pragma unroll
    for (int i = 0; i < 4; i++)
        out[(long long)(bx + ty + 8 * i) * ND + by + tx] = (bf16)tile[tx][ty + 8 * i];
}

// ---------------------------------------------------------------------------
// RoPE for Q,K only (reads fused QKV buffer, row stride 3*ND). Coalesced.
// ---------------------------------------------------------------------------
__global__ __launch_bounds__(256) void rope_qk_k(const bf16* __restrict__ QKV,
                                                 const float* __restrict__ fr,
                                                 bf16* __restrict__ Q,
                                                 bf16* __restrict__ K) {
    int gid = blockIdx.x * 256 + threadIdx.x;
    int hd = gid & 63;
    int h = (gid >> 6) & 15;
    int t = (gid >> 10) & (NT - 1);
    int bb = gid >> 20;
    float c = fr[t * 128 + hd * 2 + 0];
    float s = fr[t * 128 + hd * 2 + 1];
    long long base = ((long long)bb * NT + t) * (3 * ND) + h * NHD;
    float q1 = (float)QKV[base + hd],      q2 = (float)QKV[base + hd + 64];
    float k1 = (float)QKV[base + ND + hd], k2 = (float)QKV[base + ND + hd + 64];
    long long ob = (((long long)(bb * NH + h)) * NT + t) * NHD;
    Q[ob + hd]      = (bf16)(q1 * c - q2 * s);
    Q[ob + hd + 64] = (bf16)(q1 * s + q2 * c);
    K[ob + hd]      = (bf16)(k1 * c - k2 * s);
    K[ob + hd + 64] = (bf16)(k1 * s + k2 * c);
}

// ---------------------------------------------------------------------------
// V transpose via LDS tile: Vt[(b*16+h)][d][t] = QKV[b*NT+t][2*ND + h*128 + d].
// ---------------------------------------------------------------------------
__global__ __launch_bounds__(256) void vtr_k(const bf16* __restrict__ QKV,
                                             bf16* __restrict__ Vt) {
    __shared__ bf16 tile[64][136];   // padded: row stride 272B
    const int tt = blockIdx.x * 64;
    const int bh = blockIdx.y;
    const int bb = bh >> 4, h = bh & 15;
    const int tid = threadIdx.x;

    const int lt = tid >> 4;            // 0..15
    const int ld = (tid & 15) * 8;      // d-octet
#pragma unroll
    for (int i = 0; i < 4; i++) {
        int t = i * 16 + lt;
        bf16x8 v = *(const bf16x8*)(QKV + ((size_t)(bb * NT) + tt + t) * (3 * ND)
                                    + 2 * ND + h * NHD + ld);
        *(bf16x8*)&tile[t][ld] = v;
    }
    __syncthreads();

    const int d = tid >> 1;             // 0..127
    const int j0 = (tid & 1) * 32;      // t-half
    bf16 tmp[32];
#pragma unroll
    for (int j = 0; j < 32; j++) tmp[j] = tile[j0 + j][d];
    bf16* dst = Vt + ((size_t)bh * NHD + d) * NT + tt + j0;
#pragma unroll
    for (int j = 0; j < 4; j++)
        *(bf16x8*)(dst + j * 8) = *(const bf16x8*)(tmp + j * 8);
}

// ---------------------------------------------------------------------------
__global__ __launch_bounds__(256) void copy_k(const float4* __restrict__ in,
                                              float4* __restrict__ out, long long n) {
    for (long long i = (long long)blockIdx.x * 256 + threadIdx.x; i < n;
         i += (long long)gridDim.x * 256)
        out[i] = in[i];
}

// ---------------------------------------------------------------------------
// Fused flash attention (non-causal, mask==0, S=1024, D=128). Unchanged.
// ---------------------------------------------------------------------------
__global__ __launch_bounds__(256, 2) void flash_k(
    const bf16* __restrict__ Qr,   // [(b*16+h)][t][128]
    const bf16* __restrict__ Kr,   // [(b*16+h)][t][128]
    const bf16* __restrict__ Vt,   // [(b*16+h)][d][1024]
    bf16* __restrict__ O) {        // [b*NT+t][ND], col h*128+d
    __shared__ char lds[81920];    // K: 2x16K @0, V: 2x16K @32768, P: 4x4K @65536

    const int tid = threadIdx.x;
    const int lane = tid & 63;
    const int w = tid >> 6;
    const int lm = lane & 15, lq = lane >> 4;
    const int lm7 = lm & 7;

    const int bh = blockIdx.y;
    const int q0 = blockIdx.x * 128;
    const bf16* Qb = Qr + (size_t)bh * NT * NHD;
    const bf16* Kb = Kr + (size_t)bh * NT * NHD;
    const bf16* Vb = Vt + (size_t)bh * NHD * NT;

    const int krow = tid >> 4;
    const int kc_s = (tid & 15);
    const int vrow = tid >> 3;
    const int vc_s = (tid & 7);

    bf16x8 q[2][4];
#pragma unroll
    for (int mi = 0; mi < 2; mi++)
#pragma unroll
        for (int ks = 0; ks < 4; ks++)
            q[mi][ks] = *(const bf16x8*)(Qb + (size_t)(q0 + w * 32 + mi * 16 + lm) * NHD
                                         + lq * 8 + ks * 32);

    f32x4 o0[8], o1[8];
#pragma unroll
    for (int i = 0; i < 8; i++) {
        f32x4 zz = {0.f, 0.f, 0.f, 0.f};
        o0[i] = zz; o1[i] = zz;
    }
    float m0[4], m1[4], l0[4], l1[4];
#pragma unroll
    for (int r = 0; r < 4; r++) {
        m0[r] = -3.0e38f; m1[r] = -3.0e38f; l0[r] = 0.f; l1[r] = 0.f;
    }

    char* Pb = lds + 65536 + w * 4096;
    const float kscal = 0.08838834764831845f * 1.4426950408889634f;

#pragma unroll
    for (int i = 0; i < 4; i++) {
        int row = i * 16 + krow;
        __builtin_amdgcn_global_load_lds(
            (gptr_t)(Kb + (size_t)row * NHD + (kc_s ^ (row & 7)) * 8),
            (lptr_t)(lds + i * 4096 + tid * 16), 16, 0, 0);
    }
#pragma unroll
    for (int i = 0; i < 4; i++) {
        int row = i * 32 + vrow;
        __builtin_amdgcn_global_load_lds(
            (gptr_t)(Vb + (size_t)row * NT + (vc_s ^ (row & 7)) * 8),
            (lptr_t)(lds + 32768 + i * 4096 + tid * 16), 16, 0, 0);
    }
    __syncthreads();

    for (int c = 0; c < 16; ++c) {
        char* Kl = lds + (c & 1) * 16384;
        char* Vl = lds + 32768 + (c & 1) * 16384;

        if (c < 15) {
            const int key1 = (c + 1) * 64;
            char* Kd = lds + ((c + 1) & 1) * 16384;
            char* Vd = lds + 32768 + ((c + 1) & 1) * 16384;
#pragma unroll
            for (int i = 0; i < 4; i++) {
                int row = i * 16 + krow;
                __builtin_amdgcn_global_load_lds(
                    (gptr_t)(Kb + (size_t)(key1 + row) * NHD + (kc_s ^ (row & 7)) * 8),
                    (lptr_t)(Kd + i * 4096 + tid * 16), 16, 0, 0);
            }
#pragma unroll
            for (int i = 0; i < 4; i++) {
                int row = i * 32 + vrow;
                __builtin_amdgcn_global_load_lds(
                    (gptr_t)(Vb + (size_t)row * NT + key1 + (vc_s ^ (row & 7)) * 8),
                    (lptr_t)(Vd + i * 4096 + tid * 16), 16, 0, 0);
            }
        }

        // ---- QK^T ----
        f32x4 s0[4], s1[4];
#pragma unroll
        for (int ni = 0; ni < 4; ni++) {
            f32x4 zz = {0.f, 0.f, 0.f, 0.f};
            s0[ni] = zz; s1[ni] = zz;
        }
        __builtin_amdgcn_s_setprio(1);
#pragma unroll
        for (int ni = 0; ni < 4; ni++) {
#pragma unroll
            for (int ks = 0; ks < 4; ks++) {
                bf16x8 kf = *(const bf16x8*)(Kl + (lm + 16 * ni) * 256
                                             + (((lq + 4 * ks) ^ lm7) << 4));
                s0[ni] = __builtin_amdgcn_mfma_f32_16x16x32_bf16(q[0][ks], kf, s0[ni], 0, 0, 0);
                s1[ni] = __builtin_amdgcn_mfma_f32_16x16x32_bf16(q[1][ks], kf, s1[ni], 0, 0, 0);
            }
        }
        __builtin_amdgcn_s_setprio(0);

#pragma unroll
        for (int ni = 0; ni < 4; ni++)
#pragma unroll
            for (int r = 0; r < 4; r++) {
                s0[ni][r] *= kscal;
                s1[ni][r] *= kscal;
            }

        float sc0[4], sc1[4];
#pragma unroll
        for (int r = 0; r < 4; r++) {
            float a0 = fmaxf(fmaxf(s0[0][r], s0[1][r]), fmaxf(s0[2][r], s0[3][r]));
            float a1 = fmaxf(fmaxf(s1[0][r], s1[1][r]), fmaxf(s1[2][r], s1[3][r]));
#pragma unroll
            for (int o = 1; o < 16; o <<= 1) {
                a0 = fmaxf(a0, __shfl_xor(a0, o));
                a1 = fmaxf(a1, __shfl_xor(a1, o));
            }
            float mn0 = fmaxf(m0[r], a0);
            float mn1 = fmaxf(m1[r], a1);
            sc0[r] = exp2f(m0[r] - mn0);
            sc1[r] = exp2f(m1[r] - mn1);
            m0[r] = mn0; m1[r] = mn1;

            float rs0 = 0.f, rs1 = 0.f;
#pragma unroll
            for (int ni = 0; ni < 4; ni++) {
                float p0 = exp2f(s0[ni][r] - mn0);
                float p1 = exp2f(s1[ni][r] - mn1);
                s0[ni][r] = p0; s1[ni][r] = p1;
                rs0 += p0; rs1 += p1;
            }
#pragma unroll
            for (int o = 1; o < 16; o <<= 1) {
                rs0 += __shfl_xor(rs0, o);
                rs1 += __shfl_xor(rs1, o);
            }
            l0[r] = l0[r] * sc0[r] + rs0;
            l1[r] = l1[r] * sc1[r] + rs1;
        }
#pragma unroll
        for (int ni = 0; ni < 8; ni++)
#pragma unroll
            for (int r = 0; r < 4; r++) {
                o0[ni][r] *= sc0[r];
                o1[ni][r] *= sc1[r];
            }

#pragma unroll
        for (int ni = 0; ni < 4; ni++)
#pragma unroll
            for (int r = 0; r < 4; r++) {
                int q_l0 = lq * 4 + r;
                int q_l1 = 16 + q_l0;
                int cw = (lm >> 3) + 2 * ni;
                *(bf16*)(Pb + q_l0 * 128 + ((cw ^ (q_l0 & 7)) << 4) + (lm7 << 1)) =
                    (bf16)s0[ni][r];
                *(bf16*)(Pb + q_l1 * 128 + ((cw ^ (q_l1 & 7)) << 4) + (lm7 << 1)) =
                    (bf16)s1[ni][r];
            }
        asm volatile("s_waitcnt lgkmcnt(0)" ::: "memory");
        __builtin_amdgcn_sched_barrier(0);

        __builtin_amdgcn_s_setprio(1);
#pragma unroll
        for (int ks = 0; ks < 2; ks++) {
            bf16x8 pa0 = *(const bf16x8*)(Pb + lm * 128 + (((lq + 4 * ks) ^ lm7) << 4));
            bf16x8 pa1 = *(const bf16x8*)(Pb + (lm + 16) * 128 + (((lq + 4 * ks) ^ lm7) << 4));
#pragma unroll
            for (int ni = 0; ni < 8; ni++) {
                bf16x8 vf = *(const bf16x8*)(Vl + (lm + 16 * ni) * 128
                                             + (((lq + 4 * ks) ^ lm7) << 4));
                o0[ni] = __builtin_amdgcn_mfma_f32_16x16x32_bf16(pa0, vf, o0[ni], 0, 0, 0);
                o1[ni] = __builtin_amdgcn_mfma_f32_16x16x32_bf16(pa1, vf, o1[ni], 0, 0, 0);
            }
        }
        __builtin_amdgcn_s_setprio(0);

        __syncthreads();
    }

    const int bb = bh >> 4, h = bh & 15;
    float rl0[4], rl1[4];
#pragma unroll
    for (int r = 0; r < 4; r++) { rl0[r] = 1.f / l0[r]; rl1[r] = 1.f / l1[r]; }
#pragma unroll
    for (int ni = 0; ni < 8; ni++) {
#pragma unroll
        for (int r = 0; r < 4; r++) {
            int col = h * 128 + lm + 16 * ni;
            long long r0 = (long long)bb * NT + q0 + w * 32 + lq * 4 + r;
            O[(r0) * ND + col]      = (bf16)(o0[ni][r] * rl0[r]);
            O[(r0 + 16) * ND + col] = (bf16)(o1[ni][r] * rl1[r]);
        }
    }
}

// ---------------------------------------------------------------------------
// 256xN pipelined GEMM (BK=64, counted-lgkmcnt, 2 barriers/K-tile).
//   MODE 6 (dual-B w1/w3): A staged in LDS (2x32K), B DIRECT from global to
//     registers (L2-resident weight panels), double-buffered with prefetch
//     distance 1. VMEM issue order pinned: B(t+1) before A-DMA(t+2), so
//     counted waits are sound: compiler's wait for B(t) leaves DMA younger;
//     barrier-side vmcnt(12) drains exactly A-DMA(t+1) (8 B + 4 DMA younger).
//   NTILE=128 (MODE 2/5/7): unchanged r10 path — 4Mx2N waves (64x64/wave),
//     16 reads, 6 gloads/tile, LDS 96K; non-atomic epilogues (exclusive).
// MODE 2: C fp32 += acc (exclusive)
// MODE 5: out[(b*NS+sel[m])*ND+n] += rw[m]*(acc+res)   (exclusive)
// MODE 6: dual-B (w1,w3): C bf16 = silu(acc1)*acc3
// MODE 7: C bf16 = alpha*acc (128-N tile)
// ---------------------------------------------------------------------------
#define G256_SB() __builtin_amdgcn_sched_barrier(0)
#define G256_LGKM(n) do { asm volatile("s_waitcnt lgkmcnt(" #n ")" ::: "memory"); \
    __builtin_amdgcn_sched_barrier(0); } while (0)
#define G256_VMC(n) do { asm volatile("s_waitcnt vmcnt(" #n ")" ::: "memory"); \
    __builtin_amdgcn_sched_barrier(0); } while (0)

#define MFMA_Q(mlo, nlo) do { \
    __builtin_amdgcn_s_setprio(1); \
    _Pragma("unroll") \
    for (int _ks = 0; _ks < 2; _ks++) \
    _Pragma("unroll") \
    for (int _mi = 0; _mi < 4; _mi++) \
    _Pragma("unroll") \
    for (int _ni = 0; _ni < 2; _ni++) \
        acc[(mlo) + _mi][(nlo) + _ni] = __builtin_amdgcn_mfma_f32_16x16x32_bf16( \
            a[(mlo) + _mi][_ks], b[(nlo) + _ni][_ks], acc[(mlo) + _mi][(nlo) + _ni], \
            0, 0, 0); \
    __builtin_amdgcn_s_setprio(0); \
} while (0)

template <int MODE>
__global__ __launch_bounds__(512, 2) void gemm256(
    const bf16* __restrict__ A, int lda,
    const bf16* __restrict__ Bt, int ldb,
    void* __restrict__ Cv, int ldc,
    int K, float alpha,
    const bf16* __restrict__ Bt2,
    const float* __restrict__ res, const int* __restrict__ selp,
    const float* __restrict__ rwp, float* __restrict__ outp) {

    constexpr bool DUALB = (MODE == 6);
    constexpr bool N128  = (MODE == 2 || MODE == 5 || MODE == 7);
    constexpr int  BUFS  = DUALB ? 32768 : 49152;    // per-buffer bytes
    __shared__ char smem[2 * BUFS];                  // 64K (MODE6) / 96K (N128)

    const int tid = threadIdx.x;
    const int lane = tid & 63;
    const int wid = tid >> 6;
    // wave layout: N128 -> 4M x 2N (64x64/wave); MODE6 -> 2M x 4N (128x32-dual)
    const int wm = N128 ? (wid >> 1) : (wid >> 2);
    const int wn = N128 ? (wid & 1) : (wid & 3);
    const int lm = lane & 15, lq = lane >> 4;

    // 2D XCD mapping: xcd quadrant (2M x 4N), 8 x (nx/4) rect inside, M-first.
    // Requires ny==16, nx%4==0.
    const int nx = gridDim.x;
    const int orig = blockIdx.y * nx + blockIdx.x;
    const int xcd = orig & 7;
    const int r_ = orig >> 3;
    const int mi_ = r_ & 7, ni_ = r_ >> 3;
    const int m0 = ((xcd >> 2) * 8 + mi_) * 256;
    const int n0 = ((xcd & 3) * (nx >> 2) + ni_) * 128;   // all modes 128-N now
    const long long kz = (long long)blockIdx.z * K;

    // A staging: thread stages 16B chunk; LDS linear, global source pre-swizzled
    const int srow = tid >> 3;                 // [0,64)
    const int skc = ((tid & 7) ^ (srow & 7)) * 8;
    const long long stA = (long long)64 * lda;
    const long long stB = (long long)64 * ldb;
    const bf16* gA = A + (long long)(m0 + srow) * lda + kz + skc;
    const bf16* gB0 = Bt + (long long)(n0 + srow) * ldb + kz + skc;   // N128 only

    char* sm = (char*)smem;
    const int sdst = tid * 16;

    auto stageA = [&](int c, int t) {
        char* lA = sm + c * BUFS + sdst;
        long long ko = (long long)t * 64;
#pragma unroll
        for (int i = 0; i < 4; i++)
            __builtin_amdgcn_global_load_lds((gptr_t)(gA + i * stA + ko),
                                             (lptr_t)(lA + i * 8192), 16, 0, 0);
    };
    auto stageB_n128 = [&](int c, int t) {
        char* lB = sm + c * BUFS + 32768 + sdst;
        long long ko = (long long)t * 64;
        __builtin_amdgcn_global_load_lds((gptr_t)(gB0 + ko), (lptr_t)lB, 16, 0, 0);
        __builtin_amdgcn_global_load_lds((gptr_t)(gB0 + stB + ko),
                                         (lptr_t)(lB + 8192), 16, 0, 0);
    };

    // frag read offsets: row*128 + ((ks*4+lq) ^ (lm&7))*16 ; ks=1 is ^64
    const int swz = (lq ^ (lm & 7)) << 4;
    const int aoff = ((N128 ? wm * 64 : wm * 128) + lm) * 128 + swz;
    const int boff = ((N128 ? wn * 64 : 0) + lm) * 128 + swz;   // N128 only

    // MODE6 direct-B lane pointers: col = n0 + wn*32 + {0,16}+lm (w1 / w3)
    const bf16* bp0 = Bt  + (long long)(n0 + (DUALB ? wn * 32 : 0) + lm) * ldb + kz + lq * 8;
    const bf16* bp1 = bp0 + (long long)16 * ldb;
    const bf16* bp2 = (DUALB ? Bt2 : Bt) + (long long)(n0 + (DUALB ? wn * 32 : 0) + lm) * ldb + kz + lq * 8;
    const bf16* bp3 = bp2 + (long long)16 * ldb;

    f32x4 acc[8][4];
#pragma unroll
    for (int i = 0; i < 8; i++)
#pragma unroll
        for (int j = 0; j < 4; j++) {
            f32x4 zz = {0.f, 0.f, 0.f, 0.f};
            acc[i][j] = zz;
        }
    bf16x8 a[8][2], b[4][2], bnx[4][2];

    auto loadBdir = [&](int t) {
        long long ko = (long long)t * 64;
#pragma unroll
        for (int ks = 0; ks < 2; ks++) {
            bnx[0][ks] = *(const bf16x8*)(bp0 + ko + ks * 32);
            bnx[1][ks] = *(const bf16x8*)(bp1 + ko + ks * 32);
            bnx[2][ks] = *(const bf16x8*)(bp2 + ko + ks * 32);
            bnx[3][ks] = *(const bf16x8*)(bp3 + ko + ks * 32);
        }
    };

    auto ldA4 = [&](char* bA, int lo) {
#pragma unroll
        for (int mi2 = 0; mi2 < 4; mi2++) {
            a[lo + mi2][0] = *(const bf16x8*)(bA + aoff + (lo + mi2) * 2048);
            a[lo + mi2][1] = *(const bf16x8*)(bA + (aoff ^ 64) + (lo + mi2) * 2048);
        }
    };
    auto ldB2_n128 = [&](char* bB, int lo) {
#pragma unroll
        for (int ni2 = 0; ni2 < 2; ni2++) {
            int ix = lo + ni2;
            int o = boff + ix * 2048;
            b[ix][0] = *(const bf16x8*)(bB + o);
            b[ix][1] = *(const bf16x8*)(bB + (o ^ 64));
        }
    };

    const int NTk = K >> 6;

    if constexpr (DUALB) {
        // prologue: A(t0)->buf0 [4], B(t0) direct [8], A(t1)->buf1 [4]
        stageA(0, 0);
        loadBdir(0);
        stageA(1, 1);
        G256_VMC(4);                 // A(t0) + B(t0) done; A(t1) flying
#pragma unroll
        for (int ix = 0; ix < 4; ix++) {
            b[ix][0] = bnx[ix][0]; b[ix][1] = bnx[ix][1];
        }
        __builtin_amdgcn_s_barrier();
        G256_SB();

        for (int t = 0; t < NTk; ++t) {
            const int c = t & 1;
            char* bA = sm + c * BUFS;
            const bool more1 = (t + 1 < NTk);
            const bool more2 = (t + 2 < NTk);

            if (more1) loadBdir(t + 1);      // 8 vmem (before any DMA this tile)
            G256_SB();
            ldA4(bA, 0);
            G256_SB();
            ldA4(bA, 4);
            G256_SB();

            G256_LGKM(8);                    // first 8 A reads landed
            MFMA_Q(0, 0);
            MFMA_Q(0, 2);
            G256_LGKM(0);                    // all A reads of buf c done
            __builtin_amdgcn_s_barrier();    // release buf c
            G256_SB();
            if (more2) stageA(c, t + 2);     // 4 vmem, after B(t+1) in FIFO
            G256_SB();
            MFMA_Q(4, 0);
            MFMA_Q(4, 2);
            // drain A-DMA(t+1): younger ops = B(t+1) 8 + DMA(t+2) 4
            if (more2) { G256_VMC(12); }
            else if (more1) { G256_VMC(8); }
            else { G256_VMC(0); }
            __builtin_amdgcn_s_barrier();    // buf c^1 (tile t+1) visible
            G256_SB();
            if (more1) {
#pragma unroll
                for (int ix = 0; ix < 4; ix++) {
                    b[ix][0] = bnx[ix][0]; b[ix][1] = bnx[ix][1];
                }
            }
        }
    } else {
        // prologue: stage tile0 -> buf0, tile1 -> buf1; wait tile0
        stageA(0, 0); stageB_n128(0, 0);
        stageA(1, 1); stageB_n128(1, 1);
        G256_VMC(6);
        __builtin_amdgcn_s_barrier();
        G256_SB();

        for (int t = 0; t < NTk; ++t) {
            const int c = t & 1;
            char* bA = sm + c * BUFS;
            char* bB = bA + 32768;

            // 16 reads: A(8) + B01(4) | B23(4)
            ldA4(bA, 0);
            ldB2_n128(bB, 0);
            G256_SB();
            ldB2_n128(bB, 2);
            G256_SB();

            G256_LGKM(4);               // A + B01 landed
            MFMA_Q(0, 0);
            G256_LGKM(0);
            __builtin_amdgcn_s_barrier();
            G256_SB();
            const bool more = (t + 2 < NTk);
            if (more) { stageA(c, t + 2); stageB_n128(c, t + 2); }
            G256_SB();
            MFMA_Q(0, 2);
            if (more) { G256_VMC(6); } else { G256_VMC(0); }
            __builtin_amdgcn_s_barrier();
            G256_SB();
        }
    }

    if constexpr (MODE == 6) {
        bf16* C = (bf16*)Cv;
#pragma unroll
        for (int mi = 0; mi < 8; mi++) {
#pragma unroll
            for (int ni = 0; ni < 2; ni++) {
                const int row = m0 + wm * 128 + mi * 16 + lq * 4;
                const int col = n0 + wn * 32 + ni * 16 + lm;
#pragma unroll
                for (int r = 0; r < 4; r++) {
                    float v1 = acc[mi][ni][r];
                    float v3 = acc[mi][ni + 2][r];
                    C[(long long)(row + r) * ldc + col] =
                        (bf16)((v1 / (1.f + __expf(-v1))) * v3);
                }
            }
        }
    } else {
        // N128: 4Mx2N waves, per-wave 64x64, mi<4, ni<4
#pragma unroll
        for (int mi = 0; mi < 4; mi++) {
#pragma unroll
            for (int ni = 0; ni < 4; ni++) {
                const int row = m0 + wm * 64 + mi * 16 + lq * 4;
                const int col = n0 + wn * 64 + ni * 16 + lm;
#pragma unroll
                for (int r = 0; r < 4; r++) {
                    float v = alpha * acc[mi][ni][r];
                    long long rr = row + r;
                    if constexpr (MODE == 7) {
                        bf16* C = (bf16*)Cv;
                        C[rr * ldc + col] = (bf16)v;
                    } else if constexpr (MODE == 2) {
                        float* C = (float*)Cv;
                        C[rr * ldc + col] += v;       // exclusive tile
                    } else {   // MODE 5
                        int bb2 = (int)(rr >> 10);
                        int s = selp[rr];
                        float add = rwp[rr] * (v + res[rr * (long long)ND + col]);
                        outp[((long long)bb2 * NS + s) * ND + col] += add;  // exclusive
                    }
                }
            }
        }
    }
}

// ---------------------------------------------------------------------------
extern "C" void kernel_launch(void* const* d_in, const int* in_sizes, int n_in,
                              void* d_out, int out_size, void* d_ws, size_t ws_size,
                              hipStream_t stream) {
    const float* x  = (const float*)d_in[0];
    const float* fr = (const float*)d_in[2];
    const float* wr = (const float*)d_in[3];
    const float* g1 = (const float*)d_in[4];
    const float* wq = (const float*)d_in[5];
    const float* wk = (const float*)d_in[6];
    const float* wv = (const float*)d_in[7];
    const float* wo = (const float*)d_in[8];
    const float* g2 = (const float*)d_in[9];
    const float* w1 = (const float*)d_in[10];
    const float* w3 = (const float*)d_in[11];
    const float* w2 = (const float*)d_in[12];
    float* out = (float*)d_out;

    char* ws = (char*)d_ws;
    size_t off = 0;
    auto take = [&](size_t bytes) -> char* {
        char* p = ws + off;
        off += (bytes + 255) & ~(size_t)255;
        return p;
    };
    int*   sel    = (int*)take((size_t)NB * NT * 4);
    float* rw     = (float*)take((size_t)NB * NT * 4);
    float* logits = (float*)take((size_t)NB * NS * 4);
    float* xf     = (float*)take((size_t)NB * NT * ND * 4);
    bf16*  hbuf   = (bf16*)take((size_t)NB * NT * ND * 2);
    bf16*  wqkv_t = (bf16*)take((size_t)3 * ND * ND * 2);
    bf16*  wo_t   = (bf16*)take((size_t)ND * ND * 2);
    bf16*  Obuf   = (bf16*)take((size_t)NB * NT * ND * 2);
    char* xr = ws + off;
    // attention-phase overlay
    bf16* QKV = (bf16*)xr;                               // [4096][6144]
    bf16* Qr  = QKV + (size_t)NB * NT * 3 * ND;
    bf16* Kr  = Qr + (size_t)NB * NT * ND;
    bf16* Vt  = Kr + (size_t)NB * NT * ND;
    // FFN-phase overlay (attention data dead by then)
    bf16* w1_t  = (bf16*)xr;
    bf16* w3_t  = w1_t + (size_t)ND * NF;
    bf16* w2_t  = w3_t + (size_t)ND * NF;
    bf16* inter = w2_t + (size_t)ND * NF;

    router_k<<<NB * NS, 256, 0, stream>>>(x, wr, logits);
    topk_k<<<NB, 1024, 0, stream>>>(logits, sel, rw);
    gather_k<<<(NB * NT * ND / 4) / 256, 256, 0, stream>>>(x, sel, xf);
    rmsnorm_k<<<NB * NT, 256, 0, stream>>>(xf, g1, hbuf);

    // merged weight transposes: wq,wk,wv -> wqkv_t; wo -> wo_t (one launch)
    transpose4_nd<<<dim3(ND / 32, ND / 32, 4), 256, 0, stream>>>(
        wq, wk, wv, wo, wqkv_t, wo_t);

    // fused QKV: [4096 x 2048] x [6144 x 2048]^T -> [4096][6144]
    // 128-N tiles: grid 48x16 = 768 = 3x256 blocks, perfectly balanced
    gemm256<7><<<dim3(3 * ND / 128, NB * NT / 256, 1), 512, 0, stream>>>(
        hbuf, ND, wqkv_t, ND, QKV, 3 * ND, ND, 1.0f,
        nullptr, nullptr, nullptr, nullptr, nullptr);

    rope_qk_k<<<(NB * NT * NH * 64) / 256, 256, 0, stream>>>(QKV, fr, Qr, Kr);
    vtr_k<<<dim3(NT / 64, NB * NH), 256, 0, stream>>>(QKV, Vt);

    // fused flash attention
    flash_k<<<dim3(NT / 128, NB * NH), 256, 0, stream>>>(Qr, Kr, Vt, Obuf);

    // WO: 128-N tiles, single-z, non-atomic += into xf residual
    gemm256<2><<<dim3(ND / 128, NB * NT / 256, 1), 512, 0, stream>>>(
        Obuf, ND, wo_t, ND, xf, ND, ND, 1.0f,
        nullptr, nullptr, nullptr, nullptr, nullptr);

    rmsnorm_k<<<NB * NT, 256, 0, stream>>>(xf, g2, hbuf);

    // merged FFN weight transposes: w1 -> w1_t, w3 -> w3_t (one launch)
    transpose2_ff<<<dim3(NF / 32, ND / 32, 2), 256, 0, stream>>>(w1, w3, w1_t);
    transpose_to_bf16<<<dim3(ND / 32, NF / 32), 256, 0, stream>>>(w2, w2_t, NF, ND);

    // fused FFN up: inter = silu(h.w1) * (h.w3); B direct-from-global
    gemm256<6><<<dim3(NF / 128, NB * NT / 256, 1), 512, 0, stream>>>(
        hbuf, ND, w1_t, ND, inter, NF, ND, 1.0f,
        w3_t, nullptr, nullptr, nullptr, nullptr);

    copy_k<<<8192, 256, 0, stream>>>((const float4*)x, (float4*)out,
                                     (long long)NB * NS * ND / 4);
    // w2 + scatter-add: 128-N tiles, single-z, non-atomic (tiles exclusive)
    gemm256<5><<<dim3(ND / 128, NB * NT / 256, 1), 512, 0, stream>>>(
        inter, NF, w2_t, NF, nullptr, ND, NF, 1.0f,
        nullptr, xf, sel, rw, out);
}

// Round 12
// 1238.076 us; speedup vs baseline: 1.3135x; 1.3135x over previous
//
#include <hip/hip_runtime.h>
#include <cstdint>
#include <cstddef>

#define NB 4
#define NS 4096
#define ND 2048
#define NH 16
#define NHD 128
#define NT 1024
#define NF 8192

typedef __bf16 bf16;
typedef __bf16 bf16x8 __attribute__((ext_vector_type(8)));
typedef __bf16 bf16x4 __attribute__((ext_vector_type(4)));
typedef float  f32x4  __attribute__((ext_vector_type(4)));

typedef const __attribute__((address_space(1))) void* gptr_t;
typedef __attribute__((address_space(3))) void* lptr_t;

__device__ __forceinline__ float wave_sum(float v) {
#pragma unroll
    for (int off = 32; off > 0; off >>= 1) v += __shfl_xor(v, off);
    return v;
}
__device__ __forceinline__ float wave_max(float v) {
#pragma unroll
    for (int off = 32; off > 0; off >>= 1) v = fmaxf(v, __shfl_xor(v, off));
    return v;
}

// ---------------------------------------------------------------------------
// Router: logits[row] = dot(x[row,:], w_router)   (row = b*NS+s)
// ---------------------------------------------------------------------------
__global__ __launch_bounds__(256) void router_k(const float* __restrict__ x,
                                                const float* __restrict__ wr,
                                                float* __restrict__ logits) {
    __shared__ float r4[4];
    long long row = blockIdx.x;
    const float4* xr = (const float4*)(x + row * ND);
    const float4* w4 = (const float4*)wr;
    float p = 0.f;
    for (int i = threadIdx.x; i < ND / 4; i += 256) {
        float4 a = xr[i], b = w4[i];
        p += a.x * b.x + a.y * b.y + a.z * b.z + a.w * b.w;
    }
    p = wave_sum(p);
    if ((threadIdx.x & 63) == 0) r4[threadIdx.x >> 6] = p;
    __syncthreads();
    if (threadIdx.x == 0) logits[row] = r4[0] + r4[1] + r4[2] + r4[3];
}

// ---------------------------------------------------------------------------
// Top-K (exact, matches jax.lax.top_k tie-break) + index sort + router softmax.
// ---------------------------------------------------------------------------
__global__ __launch_bounds__(1024) void topk_k(const float* __restrict__ logits,
                                               int* __restrict__ sel,
                                               float* __restrict__ rw) {
    __shared__ unsigned long long keys[NS];   // 32 KB
    __shared__ float r16[16];
    __shared__ float bmax, bsum;
    const int bb = blockIdx.x;
    const int tid = threadIdx.x;
    const float* lg = logits + (long long)bb * NS;

    for (int i = tid; i < NS; i += 1024) {
        unsigned u = __float_as_uint(lg[i]);
        u = (u & 0x80000000u) ? ~u : (u | 0x80000000u);   // order-preserving map
        keys[i] = ((unsigned long long)u << 32) | (unsigned)(NS - 1 - i);
    }
    __syncthreads();
    for (int k = 2; k <= NS; k <<= 1) {
        for (int j = k >> 1; j > 0; j >>= 1) {
            for (int i = tid; i < NS; i += 1024) {
                int ixj = i ^ j;
                if (ixj > i) {
                    unsigned long long a = keys[i], c = keys[ixj];
                    bool up = ((i & k) == 0);
                    if (up ? (a < c) : (a > c)) { keys[i] = c; keys[ixj] = a; }
                }
            }
            __syncthreads();
        }
    }
    unsigned long long a0 = keys[tid];
    __syncthreads();
    {
        unsigned idx_ = NS - 1 - (unsigned)(a0 & 0xFFFFFFFFu);
        unsigned uval = (unsigned)(a0 >> 32);
        keys[tid] = ((unsigned long long)idx_ << 32) | uval;
    }
    __syncthreads();
    for (int k = 2; k <= NT; k <<= 1) {
        for (int j = k >> 1; j > 0; j >>= 1) {
            int i = tid, ixj = i ^ j;
            if (i < NT && ixj > i) {
                unsigned long long a = keys[i], c = keys[ixj];
                bool up = ((i & k) == 0);
                if (up ? (a > c) : (a < c)) { keys[i] = c; keys[ixj] = a; }
            }
            __syncthreads();
        }
    }
    unsigned long long kk = keys[tid];
    int si = (int)(kk >> 32);
    unsigned u = (unsigned)(kk & 0xFFFFFFFFu);
    u = (u & 0x80000000u) ? (u ^ 0x80000000u) : ~u;
    float val = __uint_as_float(u);

    const int wid = tid >> 6, lane = tid & 63;
    float mx = wave_max(val);
    if (lane == 0) r16[wid] = mx;
    __syncthreads();
    if (tid == 0) {
        float m = r16[0];
        for (int i = 1; i < 16; i++) m = fmaxf(m, r16[i]);
        bmax = m;
    }
    __syncthreads();
    float e = __expf(val - bmax);
    float s = wave_sum(e);
    if (lane == 0) r16[wid] = s;
    __syncthreads();
    if (tid == 0) {
        float t = 0.f;
        for (int i = 0; i < 16; i++) t += r16[i];
        bsum = t;
    }
    __syncthreads();
    sel[bb * NT + tid] = si;
    rw[bb * NT + tid] = e / bsum;
}

// ---------------------------------------------------------------------------
// Gather: xf[b,j,:] = x[b, sel[b,j], :]   (float4)
// ---------------------------------------------------------------------------
__global__ __launch_bounds__(256) void gather_k(const float* __restrict__ x,
                                                const int* __restrict__ sel,
                                                float* __restrict__ xf) {
    int gid = blockIdx.x * 256 + threadIdx.x;
    int col = gid & (ND / 4 - 1);
    int row = gid >> 9;
    int bb = row >> 10;
    int s = sel[row];
    ((float4*)xf)[gid] = ((const float4*)x)[((long long)bb * NS + s) * (ND / 4) + col];
}

// ---------------------------------------------------------------------------
// RMSNorm row kernel: out = bf16(x * rsqrt(mean(x^2)+eps) * g)
// ---------------------------------------------------------------------------
__global__ __launch_bounds__(256) void rmsnorm_k(const float* __restrict__ x,
                                                 const float* __restrict__ g,
                                                 bf16* __restrict__ out) {
    __shared__ float r4[4];
    __shared__ float scl;
    long long row = blockIdx.x;
    const float4* xr = (const float4*)(x + row * ND);
    int i0 = threadIdx.x, i1 = threadIdx.x + 256;
    float4 a = xr[i0], b = xr[i1];
    float ss = a.x * a.x + a.y * a.y + a.z * a.z + a.w * a.w +
               b.x * b.x + b.y * b.y + b.z * b.z + b.w * b.w;
    ss = wave_sum(ss);
    if ((threadIdx.x & 63) == 0) r4[threadIdx.x >> 6] = ss;
    __syncthreads();
    if (threadIdx.x == 0)
        scl = rsqrtf((r4[0] + r4[1] + r4[2] + r4[3]) * (1.0f / ND) + 1e-6f);
    __syncthreads();
    float s = scl;
    const float4* g4 = (const float4*)g;
    float4 ga = g4[i0], gb = g4[i1];
    bf16x4 o0, o1;
    o0[0] = (bf16)(a.x * s * ga.x); o0[1] = (bf16)(a.y * s * ga.y);
    o0[2] = (bf16)(a.z * s * ga.z); o0[3] = (bf16)(a.w * s * ga.w);
    o1[0] = (bf16)(b.x * s * gb.x); o1[1] = (bf16)(b.y * s * gb.y);
    o1[2] = (bf16)(b.z * s * gb.z); o1[3] = (bf16)(b.w * s * gb.w);
    *(bf16x4*)(out + row * ND + i0 * 4) = o0;
    *(bf16x4*)(out + row * ND + i1 * 4) = o1;
}

// ---------------------------------------------------------------------------
// Transpose + fp32->bf16: out[c][r] = in[r][c]; in is R x C. dims %32 == 0.
// ---------------------------------------------------------------------------
__global__ __launch_bounds__(256) void transpose_to_bf16(const float* __restrict__ in,
                                                         bf16* __restrict__ out,
                                                         int R, int C) {
    __shared__ float tile[32][33];
    int bx = blockIdx.x * 32;   // col
    int by = blockIdx.y * 32;   // row
    int tx = threadIdx.x & 31;
    int ty = threadIdx.x >> 5;   // 0..7
#pragma unroll
    for (int i = 0; i < 4; i++)
        tile[ty + 8 * i][tx] = in[(long long)(by + ty + 8 * i) * C + bx + tx];
    __syncthreads();
#pragma unroll
    for (int i = 0; i < 4; i++)
        out[(long long)(bx + ty + 8 * i) * R + by + tx] = (bf16)tile[tx][ty + 8 * i];
}

// ---------------------------------------------------------------------------
// RoPE for Q,K only (reads fused QKV buffer, row stride 3*ND). Coalesced.
// ---------------------------------------------------------------------------
__global__ __launch_bounds__(256) void rope_qk_k(const bf16* __restrict__ QKV,
                                                 const float* __restrict__ fr,
                                                 bf16* __restrict__ Q,
                                                 bf16* __restrict__ K) {
    int gid = blockIdx.x * 256 + threadIdx.x;
    int hd = gid & 63;
    int h = (gid >> 6) & 15;
    int t = (gid >> 10) & (NT - 1);
    int bb = gid >> 20;
    float c = fr[t * 128 + hd * 2 + 0];
    float s = fr[t * 128 + hd * 2 + 1];
    long long base = ((long long)bb * NT + t) * (3 * ND) + h * NHD;
    float q1 = (float)QKV[base + hd],      q2 = (float)QKV[base + hd + 64];
    float k1 = (float)QKV[base + ND + hd], k2 = (float)QKV[base + ND + hd + 64];
    long long ob = (((long long)(bb * NH + h)) * NT + t) * NHD;
    Q[ob + hd]      = (bf16)(q1 * c - q2 * s);
    Q[ob + hd + 64] = (bf16)(q1 * s + q2 * c);
    K[ob + hd]      = (bf16)(k1 * c - k2 * s);
    K[ob + hd + 64] = (bf16)(k1 * s + k2 * c);
}

// ---------------------------------------------------------------------------
// V transpose via LDS tile: Vt[(b*16+h)][d][t] = QKV[b*NT+t][2*ND + h*128 + d].
// ---------------------------------------------------------------------------
__global__ __launch_bounds__(256) void vtr_k(const bf16* __restrict__ QKV,
                                             bf16* __restrict__ Vt) {
    __shared__ bf16 tile[64][136];   // padded: row stride 272B
    const int tt = blockIdx.x * 64;
    const int bh = blockIdx.y;
    const int bb = bh >> 4, h = bh & 15;
    const int tid = threadIdx.x;

    const int lt = tid >> 4;            // 0..15
    const int ld = (tid & 15) * 8;      // d-octet
#pragma unroll
    for (int i = 0; i < 4; i++) {
        int t = i * 16 + lt;
        bf16x8 v = *(const bf16x8*)(QKV + ((size_t)(bb * NT) + tt + t) * (3 * ND)
                                    + 2 * ND + h * NHD + ld);
        *(bf16x8*)&tile[t][ld] = v;
    }
    __syncthreads();

    const int d = tid >> 1;             // 0..127
    const int j0 = (tid & 1) * 32;      // t-half
    bf16 tmp[32];
#pragma unroll
    for (int j = 0; j < 32; j++) tmp[j] = tile[j0 + j][d];
    bf16* dst = Vt + ((size_t)bh * NHD + d) * NT + tt + j0;
#pragma unroll
    for (int j = 0; j < 4; j++)
        *(bf16x8*)(dst + j * 8) = *(const bf16x8*)(tmp + j * 8);
}

// ---------------------------------------------------------------------------
__global__ __launch_bounds__(256) void copy_k(const float4* __restrict__ in,
                                              float4* __restrict__ out, long long n) {
    for (long long i = (long long)blockIdx.x * 256 + threadIdx.x; i < n;
         i += (long long)gridDim.x * 256)
        out[i] = in[i];
}

// ---------------------------------------------------------------------------
// Fused flash attention (non-causal, mask==0, S=1024, D=128).
// ---------------------------------------------------------------------------
__global__ __launch_bounds__(256, 2) void flash_k(
    const bf16* __restrict__ Qr,   // [(b*16+h)][t][128]
    const bf16* __restrict__ Kr,   // [(b*16+h)][t][128]
    const bf16* __restrict__ Vt,   // [(b*16+h)][d][1024]
    bf16* __restrict__ O) {        // [b*NT+t][ND], col h*128+d
    __shared__ char lds[81920];    // K: 2x16K @0, V: 2x16K @32768, P: 4x4K @65536

    const int tid = threadIdx.x;
    const int lane = tid & 63;
    const int w = tid >> 6;
    const int lm = lane & 15, lq = lane >> 4;
    const int lm7 = lm & 7;

    const int bh = blockIdx.y;
    const int q0 = blockIdx.x * 128;
    const bf16* Qb = Qr + (size_t)bh * NT * NHD;
    const bf16* Kb = Kr + (size_t)bh * NT * NHD;
    const bf16* Vb = Vt + (size_t)bh * NHD * NT;

    const int krow = tid >> 4;
    const int kc_s = (tid & 15);
    const int vrow = tid >> 3;
    const int vc_s = (tid & 7);

    bf16x8 q[2][4];
#pragma unroll
    for (int mi = 0; mi < 2; mi++)
#pragma unroll
        for (int ks = 0; ks < 4; ks++)
            q[mi][ks] = *(const bf16x8*)(Qb + (size_t)(q0 + w * 32 + mi * 16 + lm) * NHD
                                         + lq * 8 + ks * 32);

    f32x4 o0[8], o1[8];
#pragma unroll
    for (int i = 0; i < 8; i++) {
        f32x4 zz = {0.f, 0.f, 0.f, 0.f};
        o0[i] = zz; o1[i] = zz;
    }
    float m0[4], m1[4], l0[4], l1[4];
#pragma unroll
    for (int r = 0; r < 4; r++) {
        m0[r] = -3.0e38f; m1[r] = -3.0e38f; l0[r] = 0.f; l1[r] = 0.f;
    }

    char* Pb = lds + 65536 + w * 4096;
    const float kscal = 0.08838834764831845f * 1.4426950408889634f;

#pragma unroll
    for (int i = 0; i < 4; i++) {
        int row = i * 16 + krow;
        __builtin_amdgcn_global_load_lds(
            (gptr_t)(Kb + (size_t)row * NHD + (kc_s ^ (row & 7)) * 8),
            (lptr_t)(lds + i * 4096 + tid * 16), 16, 0, 0);
    }
#pragma unroll
    for (int i = 0; i < 4; i++) {
        int row = i * 32 + vrow;
        __builtin_amdgcn_global_load_lds(
            (gptr_t)(Vb + (size_t)row * NT + (vc_s ^ (row & 7)) * 8),
            (lptr_t)(lds + 32768 + i * 4096 + tid * 16), 16, 0, 0);
    }
    __syncthreads();

    for (int c = 0; c < 16; ++c) {
        char* Kl = lds + (c & 1) * 16384;
        char* Vl = lds + 32768 + (c & 1) * 16384;

        if (c < 15) {
            const int key1 = (c + 1) * 64;
            char* Kd = lds + ((c + 1) & 1) * 16384;
            char* Vd = lds + 32768 + ((c + 1) & 1) * 16384;
#pragma unroll
            for (int i = 0; i < 4; i++) {
                int row = i * 16 + krow;
                __builtin_amdgcn_global_load_lds(
                    (gptr_t)(Kb + (size_t)(key1 + row) * NHD + (kc_s ^ (row & 7)) * 8),
                    (lptr_t)(Kd + i * 4096 + tid * 16), 16, 0, 0);
            }
#pragma unroll
            for (int i = 0; i < 4; i++) {
                int row = i * 32 + vrow;
                __builtin_amdgcn_global_load_lds(
                    (gptr_t)(Vb + (size_t)row * NT + key1 + (vc_s ^ (row & 7)) * 8),
                    (lptr_t)(Vd + i * 4096 + tid * 16), 16, 0, 0);
            }
        }

        // ---- QK^T ----
        f32x4 s0[4], s1[4];
#pragma unroll
        for (int ni = 0; ni < 4; ni++) {
            f32x4 zz = {0.f, 0.f, 0.f, 0.f};
            s0[ni] = zz; s1[ni] = zz;
        }
        __builtin_amdgcn_s_setprio(1);
#pragma unroll
        for (int ni = 0; ni < 4; ni++) {
#pragma unroll
            for (int ks = 0; ks < 4; ks++) {
                bf16x8 kf = *(const bf16x8*)(Kl + (lm + 16 * ni) * 256
                                             + (((lq + 4 * ks) ^ lm7) << 4));
                s0[ni] = __builtin_amdgcn_mfma_f32_16x16x32_bf16(q[0][ks], kf, s0[ni], 0, 0, 0);
                s1[ni] = __builtin_amdgcn_mfma_f32_16x16x32_bf16(q[1][ks], kf, s1[ni], 0, 0, 0);
            }
        }
        __builtin_amdgcn_s_setprio(0);

#pragma unroll
        for (int ni = 0; ni < 4; ni++)
#pragma unroll
            for (int r = 0; r < 4; r++) {
                s0[ni][r] *= kscal;
                s1[ni][r] *= kscal;
            }

        float sc0[4], sc1[4];
#pragma unroll
        for (int r = 0; r < 4; r++) {
            float a0 = fmaxf(fmaxf(s0[0][r], s0[1][r]), fmaxf(s0[2][r], s0[3][r]));
            float a1 = fmaxf(fmaxf(s1[0][r], s1[1][r]), fmaxf(s1[2][r], s1[3][r]));
#pragma unroll
            for (int o = 1; o < 16; o <<= 1) {
                a0 = fmaxf(a0, __shfl_xor(a0, o));
                a1 = fmaxf(a1, __shfl_xor(a1, o));
            }
            float mn0 = fmaxf(m0[r], a0);
            float mn1 = fmaxf(m1[r], a1);
            sc0[r] = exp2f(m0[r] - mn0);
            sc1[r] = exp2f(m1[r] - mn1);
            m0[r] = mn0; m1[r] = mn1;

            float rs0 = 0.f, rs1 = 0.f;
#pragma unroll
            for (int ni = 0; ni < 4; ni++) {
                float p0 = exp2f(s0[ni][r] - mn0);
                float p1 = exp2f(s1[ni][r] - mn1);
                s0[ni][r] = p0; s1[ni][r] = p1;
                rs0 += p0; rs1 += p1;
            }
#pragma unroll
            for (int o = 1; o < 16; o <<= 1) {
                rs0 += __shfl_xor(rs0, o);
                rs1 += __shfl_xor(rs1, o);
            }
            l0[r] = l0[r] * sc0[r] + rs0;
            l1[r] = l1[r] * sc1[r] + rs1;
        }
#pragma unroll
        for (int ni = 0; ni < 8; ni++)
#pragma unroll
            for (int r = 0; r < 4; r++) {
                o0[ni][r] *= sc0[r];
                o1[ni][r] *= sc1[r];
            }

#pragma unroll
        for (int ni = 0; ni < 4; ni++)
#pragma unroll
            for (int r = 0; r < 4; r++) {
                int q_l0 = lq * 4 + r;
                int q_l1 = 16 + q_l0;
                int cw = (lm >> 3) + 2 * ni;
                *(bf16*)(Pb + q_l0 * 128 + ((cw ^ (q_l0 & 7)) << 4) + (lm7 << 1)) =
                    (bf16)s0[ni][r];
                *(bf16*)(Pb + q_l1 * 128 + ((cw ^ (q_l1 & 7)) << 4) + (lm7 << 1)) =
                    (bf16)s1[ni][r];
            }
        asm volatile("s_waitcnt lgkmcnt(0)" ::: "memory");
        __builtin_amdgcn_sched_barrier(0);

        __builtin_amdgcn_s_setprio(1);
#pragma unroll
        for (int ks = 0; ks < 2; ks++) {
            bf16x8 pa0 = *(const bf16x8*)(Pb + lm * 128 + (((lq + 4 * ks) ^ lm7) << 4));
            bf16x8 pa1 = *(const bf16x8*)(Pb + (lm + 16) * 128 + (((lq + 4 * ks) ^ lm7) << 4));
#pragma unroll
            for (int ni = 0; ni < 8; ni++) {
                bf16x8 vf = *(const bf16x8*)(Vl + (lm + 16 * ni) * 128
                                             + (((lq + 4 * ks) ^ lm7) << 4));
                o0[ni] = __builtin_amdgcn_mfma_f32_16x16x32_bf16(pa0, vf, o0[ni], 0, 0, 0);
                o1[ni] = __builtin_amdgcn_mfma_f32_16x16x32_bf16(pa1, vf, o1[ni], 0, 0, 0);
            }
        }
        __builtin_amdgcn_s_setprio(0);

        __syncthreads();
    }

    const int bb = bh >> 4, h = bh & 15;
    float rl0[4], rl1[4];
#pragma unroll
    for (int r = 0; r < 4; r++) { rl0[r] = 1.f / l0[r]; rl1[r] = 1.f / l1[r]; }
#pragma unroll
    for (int ni = 0; ni < 8; ni++) {
#pragma unroll
        for (int r = 0; r < 4; r++) {
            int col = h * 128 + lm + 16 * ni;
            long long r0 = (long long)bb * NT + q0 + w * 32 + lq * 4 + r;
            O[(r0) * ND + col]      = (bf16)(o0[ni][r] * rl0[r]);
            O[(r0 + 16) * ND + col] = (bf16)(o1[ni][r] * rl1[r]);
        }
    }
}

// ---------------------------------------------------------------------------
// 256xN pipelined GEMM (r7 version: BK=64, counted-lgkmcnt, 2 barriers/K-tile).
//   NTILE=256 (MODE 0/6): 24 reads, 8 gloads/tile, LDS 128K.
//   NTILE=128 (MODE 2/5): 20 reads, 6 gloads/tile, LDS 96K; non-atomic
//   epilogues (exclusive tiles).
// MODE 0: C bf16 = alpha*acc          MODE 2: C fp32 += acc (exclusive)
// MODE 5: out[(b*NS+sel[m])*ND+n] += rw[m]*(acc+res)   (exclusive)
// MODE 6: dual-B (w1,w3): C bf16 = silu(acc1)*acc3
// ---------------------------------------------------------------------------
#define G256_SB() __builtin_amdgcn_sched_barrier(0)
#define G256_LGKM(n) do { asm volatile("s_waitcnt lgkmcnt(" #n ")" ::: "memory"); \
    __builtin_amdgcn_sched_barrier(0); } while (0)
#define G256_VMC(n) do { asm volatile("s_waitcnt vmcnt(" #n ")" ::: "memory"); \
    __builtin_amdgcn_sched_barrier(0); } while (0)

#define MFMA_Q(mlo, nlo) do { \
    __builtin_amdgcn_s_setprio(1); \
    _Pragma("unroll") \
    for (int _ks = 0; _ks < 2; _ks++) \
    _Pragma("unroll") \
    for (int _mi = 0; _mi < 4; _mi++) \
    _Pragma("unroll") \
    for (int _ni = 0; _ni < 2; _ni++) \
        acc[(mlo) + _mi][(nlo) + _ni] = __builtin_amdgcn_mfma_f32_16x16x32_bf16( \
            a[(mlo) + _mi][_ks], b[(nlo) + _ni][_ks], acc[(mlo) + _mi][(nlo) + _ni], \
            0, 0, 0); \
    __builtin_amdgcn_s_setprio(0); \
} while (0)

template <int MODE>
__global__ __launch_bounds__(512, 2) void gemm256(
    const bf16* __restrict__ A, int lda,
    const bf16* __restrict__ Bt, int ldb,
    void* __restrict__ Cv, int ldc,
    int K, float alpha,
    const bf16* __restrict__ Bt2,
    const float* __restrict__ res, const int* __restrict__ selp,
    const float* __restrict__ rwp, float* __restrict__ outp) {

    constexpr bool DUALB = (MODE == 6);
    constexpr bool N128  = (MODE == 2 || MODE == 5);
    constexpr bool NI4   = !N128;                    // 4 B-frag pairs
    constexpr int  BBUF  = N128 ? 16384 : 32768;     // B bytes per buffer
    constexpr int  BUFS  = 32768 + BBUF;             // per-buffer bytes
    constexpr int  bw    = (DUALB || N128) ? 32 : 64;   // cols per wave
    constexpr int  bStep2 = DUALB ? 16384 : 4096;    // ni-pair 1 byte offset
    constexpr int  NIE   = (DUALB || N128) ? 2 : 4;  // epilogue ni count
    __shared__ char smem[2 * BUFS];

    const int tid = threadIdx.x;
    const int lane = tid & 63;
    const int wid = tid >> 6;
    const int wm = wid >> 2, wn = wid & 3;     // 2 x 4 waves
    const int lm = lane & 15, lq = lane >> 4;

    // 2D XCD mapping: xcd quadrant (2M x 4N), 8 x (nx/4) rect inside, M-first.
    // Requires ny==16, nx%4==0.
    const int nx = gridDim.x;
    const int orig = blockIdx.y * nx + blockIdx.x;
    const int xcd = orig & 7;
    const int r_ = orig >> 3;
    const int mi_ = r_ & 7, ni_ = r_ >> 3;
    const int nT = (DUALB || N128) ? 128 : 256;
    const int m0 = ((xcd >> 2) * 8 + mi_) * 256;
    const int n0 = ((xcd & 3) * (nx >> 2) + ni_) * nT;
    const long long kz = (long long)blockIdx.z * K;

    // staging: thread stages 16B chunk; LDS linear, global source pre-swizzled
    const int srow = tid >> 3;                 // [0,64)
    const int skc = ((tid & 7) ^ (srow & 7)) * 8;
    const long long stA = (long long)64 * lda;
    const long long stB = (long long)64 * ldb;
    const bf16* gA = A + (long long)(m0 + srow) * lda + kz + skc;
    const bf16* gB0 = Bt + (long long)(n0 + srow) * ldb + kz + skc;
    const bf16* gB2 = DUALB ? Bt2 + (long long)(n0 + srow) * ldb + kz + skc
                            : gB0 + 2 * stB;

    char* sm = (char*)smem;
    const int sdst = tid * 16;

    auto stage = [&](int c, int t) {
        char* lA = sm + c * BUFS + sdst;
        long long ko = (long long)t * 64;
#pragma unroll
        for (int i = 0; i < 4; i++)
            __builtin_amdgcn_global_load_lds((gptr_t)(gA + i * stA + ko),
                                             (lptr_t)(lA + i * 8192), 16, 0, 0);
        char* lB = sm + c * BUFS + 32768 + sdst;
        __builtin_amdgcn_global_load_lds((gptr_t)(gB0 + ko), (lptr_t)lB, 16, 0, 0);
        __builtin_amdgcn_global_load_lds((gptr_t)(gB0 + stB + ko),
                                         (lptr_t)(lB + 8192), 16, 0, 0);
        if constexpr (NI4) {
            __builtin_amdgcn_global_load_lds((gptr_t)(gB2 + ko),
                                             (lptr_t)(lB + 16384), 16, 0, 0);
            __builtin_amdgcn_global_load_lds((gptr_t)(gB2 + stB + ko),
                                             (lptr_t)(lB + 24576), 16, 0, 0);
        }
    };

    // frag read offsets: row*128 + ((ks*4+lq) ^ (lm&7))*16 ; ks=1 is ^64
    const int aoff = (wm * 128 + lm) * 128 + ((lq ^ (lm & 7)) << 4);
    const int boff = (wn * bw + lm) * 128 + ((lq ^ (lm & 7)) << 4);

    f32x4 acc[8][4];
#pragma unroll
    for (int i = 0; i < 8; i++)
#pragma unroll
        for (int j = 0; j < 4; j++) {
            f32x4 zz = {0.f, 0.f, 0.f, 0.f};
            acc[i][j] = zz;
        }
    bf16x8 a[8][2], b[4][2];

    auto ldA4 = [&](char* bA, int lo) {
#pragma unroll
        for (int mi2 = 0; mi2 < 4; mi2++) {
            a[lo + mi2][0] = *(const bf16x8*)(bA + aoff + (lo + mi2) * 2048);
            a[lo + mi2][1] = *(const bf16x8*)(bA + (aoff ^ 64) + (lo + mi2) * 2048);
        }
    };
    auto ldB2 = [&](char* bB, int lo) {
#pragma unroll
        for (int ni2 = 0; ni2 < 2; ni2++) {
            int ix = lo + ni2;
            int o = boff + (ix & 1) * 2048 + (ix >> 1) * bStep2;
            b[ix][0] = *(const bf16x8*)(bB + o);
            b[ix][1] = *(const bf16x8*)(bB + (o ^ 64));
        }
    };

    const int NTk = K >> 6;

    // prologue: stage tile0 -> buf0, tile1 -> buf1; wait tile0
    stage(0, 0);
    stage(1, 1);
    if constexpr (NI4) { G256_VMC(8); } else { G256_VMC(6); }
    __builtin_amdgcn_s_barrier();
    G256_SB();

    for (int t = 0; t < NTk; ++t) {
        const int c = t & 1;
        char* bA = sm + c * BUFS;
        char* bB = bA + 32768;

        // issue all frag reads; group order pinned (counts depend on it)
        ldA4(bA, 0);
        ldB2(bB, 0);           // group1: 12 reads
        G256_SB();
        if constexpr (NI4) {
            ldB2(bB, 2);       // group2: 4 reads
            G256_SB();
        }
        ldA4(bA, 4);           // group3: 8 reads
        G256_SB();

        if constexpr (NI4) { G256_LGKM(12); } else { G256_LGKM(8); }
        MFMA_Q(0, 0);
        if constexpr (NI4) {
            G256_LGKM(8);
            MFMA_Q(0, 2);
        }
        G256_LGKM(0);                        // all reads of buf c done
        __builtin_amdgcn_s_barrier();        // release buf c
        G256_SB();
        const bool more = (t + 2 < NTk);
        if (more) stage(c, t + 2);           // overwrite buf c with t+2
        G256_SB();
        MFMA_Q(4, 0);                        // overlaps staging
        if constexpr (NI4) MFMA_Q(4, 2);
        if (more) {
            if constexpr (NI4) { G256_VMC(8); } else { G256_VMC(6); }
        } else {
            G256_VMC(0);
        }
        __builtin_amdgcn_s_barrier();        // buf c^1 (tile t+1) visible
        G256_SB();
    }

    if constexpr (MODE == 6) {
        bf16* C = (bf16*)Cv;
#pragma unroll
        for (int mi = 0; mi < 8; mi++) {
#pragma unroll
            for (int ni = 0; ni < 2; ni++) {
                const int row = m0 + wm * 128 + mi * 16 + lq * 4;
                const int col = n0 + wn * 32 + ni * 16 + lm;
#pragma unroll
                for (int r = 0; r < 4; r++) {
                    float v1 = acc[mi][ni][r];
                    float v3 = acc[mi][ni + 2][r];
                    C[(long long)(row + r) * ldc + col] =
                        (bf16)((v1 / (1.f + __expf(-v1))) * v3);
                }
            }
        }
    } else {
#pragma unroll
        for (int mi = 0; mi < 8; mi++) {
#pragma unroll
            for (int ni = 0; ni < NIE; ni++) {
                const int row = m0 + wm * 128 + mi * 16 + lq * 4;
                const int col = n0 + wn * bw + ni * 16 + lm;
#pragma unroll
                for (int r = 0; r < 4; r++) {
                    float v = alpha * acc[mi][ni][r];
                    long long rr = row + r;
                    if constexpr (MODE == 0) {
                        bf16* C = (bf16*)Cv;
                        C[rr * ldc + col] = (bf16)v;
                    } else if constexpr (MODE == 2) {
                        float* C = (float*)Cv;
                        C[rr * ldc + col] += v;       // exclusive tile
                    } else {   // MODE 5
                        int bb2 = (int)(rr >> 10);
                        int s = selp[rr];
                        float add = rwp[rr] * (v + res[rr * (long long)ND + col]);
                        outp[((long long)bb2 * NS + s) * ND + col] += add;  // exclusive
                    }
                }
            }
        }
    }
}

// ---------------------------------------------------------------------------
extern "C" void kernel_launch(void* const* d_in, const int* in_sizes, int n_in,
                              void* d_out, int out_size, void* d_ws, size_t ws_size,
                              hipStream_t stream) {
    const float* x  = (const float*)d_in[0];
    const float* fr = (const float*)d_in[2];
    const float* wr = (const float*)d_in[3];
    const float* g1 = (const float*)d_in[4];
    const float* wq = (const float*)d_in[5];
    const float* wk = (const float*)d_in[6];
    const float* wv = (const float*)d_in[7];
    const float* wo = (const float*)d_in[8];
    const float* g2 = (const float*)d_in[9];
    const float* w1 = (const float*)d_in[10];
    const float* w3 = (const float*)d_in[11];
    const float* w2 = (const float*)d_in[12];
    float* out = (float*)d_out;

    char* ws = (char*)d_ws;
    size_t off = 0;
    auto take = [&](size_t bytes) -> char* {
        char* p = ws + off;
        off += (bytes + 255) & ~(size_t)255;
        return p;
    };
    int*   sel    = (int*)take((size_t)NB * NT * 4);
    float* rw     = (float*)take((size_t)NB * NT * 4);
    float* logits = (float*)take((size_t)NB * NS * 4);
    float* xf     = (float*)take((size_t)NB * NT * ND * 4);
    bf16*  hbuf   = (bf16*)take((size_t)NB * NT * ND * 2);
    bf16*  wqkv_t = (bf16*)take((size_t)3 * ND * ND * 2);
    bf16*  wo_t   = (bf16*)take((size_t)ND * ND * 2);
    bf16*  Obuf   = (bf16*)take((size_t)NB * NT * ND * 2);
    char* xr = ws + off;
    // attention-phase overlay
    bf16* QKV = (bf16*)xr;                               // [4096][6144]
    bf16* Qr  = QKV + (size_t)NB * NT * 3 * ND;
    bf16* Kr  = Qr + (size_t)NB * NT * ND;
    bf16* Vt  = Kr + (size_t)NB * NT * ND;
    // FFN-phase overlay (attention data dead by then)
    bf16* w1_t  = (bf16*)xr;
    bf16* w3_t  = w1_t + (size_t)ND * NF;
    bf16* w2_t  = w3_t + (size_t)ND * NF;
    bf16* inter = w2_t + (size_t)ND * NF;

    router_k<<<NB * NS, 256, 0, stream>>>(x, wr, logits);
    topk_k<<<NB, 1024, 0, stream>>>(logits, sel, rw);
    gather_k<<<(NB * NT * ND / 4) / 256, 256, 0, stream>>>(x, sel, xf);
    rmsnorm_k<<<NB * NT, 256, 0, stream>>>(xf, g1, hbuf);

    dim3 tg(ND / 32, ND / 32);
    transpose_to_bf16<<<tg, 256, 0, stream>>>(wq, wqkv_t, ND, ND);
    transpose_to_bf16<<<tg, 256, 0, stream>>>(wk, wqkv_t + (size_t)ND * ND, ND, ND);
    transpose_to_bf16<<<tg, 256, 0, stream>>>(wv, wqkv_t + (size_t)2 * ND * ND, ND, ND);
    transpose_to_bf16<<<tg, 256, 0, stream>>>(wo, wo_t, ND, ND);

    // fused QKV: [4096 x 2048] x [6144 x 2048]^T -> [4096][6144]
    gemm256<0><<<dim3(3 * ND / 256, NB * NT / 256, 1), 512, 0, stream>>>(
        hbuf, ND, wqkv_t, ND, QKV, 3 * ND, ND, 1.0f,
        nullptr, nullptr, nullptr, nullptr, nullptr);

    rope_qk_k<<<(NB * NT * NH * 64) / 256, 256, 0, stream>>>(QKV, fr, Qr, Kr);
    vtr_k<<<dim3(NT / 64, NB * NH), 256, 0, stream>>>(QKV, Vt);

    // fused flash attention
    flash_k<<<dim3(NT / 128, NB * NH), 256, 0, stream>>>(Qr, Kr, Vt, Obuf);

    // WO: 128-N tiles, single-z, non-atomic += into xf residual
    gemm256<2><<<dim3(ND / 128, NB * NT / 256, 1), 512, 0, stream>>>(
        Obuf, ND, wo_t, ND, xf, ND, ND, 1.0f,
        nullptr, nullptr, nullptr, nullptr, nullptr);

    rmsnorm_k<<<NB * NT, 256, 0, stream>>>(xf, g2, hbuf);

    transpose_to_bf16<<<dim3(NF / 32, ND / 32), 256, 0, stream>>>(w1, w1_t, ND, NF);
    transpose_to_bf16<<<dim3(NF / 32, ND / 32), 256, 0, stream>>>(w3, w3_t, ND, NF);
    transpose_to_bf16<<<dim3(ND / 32, NF / 32), 256, 0, stream>>>(w2, w2_t, NF, ND);

    // fused FFN up: inter = silu(h.w1) * (h.w3)
    gemm256<6><<<dim3(NF / 128, NB * NT / 256, 1), 512, 0, stream>>>(
        hbuf, ND, w1_t, ND, inter, NF, ND, 1.0f,
        w3_t, nullptr, nullptr, nullptr, nullptr);

    copy_k<<<8192, 256, 0, stream>>>((const float4*)x, (float4*)out,
                                     (long long)NB * NS * ND / 4);
    // w2 + scatter-add: 128-N tiles, single-z, non-atomic (tiles exclusive)
    gemm256<5><<<dim3(ND / 128, NB * NT / 256, 1), 512, 0, stream>>>(
        inter, NF, w2_t, NF, nullptr, ND, NF, 1.0f,
        nullptr, xf, sel, rw, out);
}

// Round 13
// 1192.697 us; speedup vs baseline: 1.3634x; 1.0380x over previous
//
#include <hip/hip_runtime.h>
#include <cstdint>
#include <cstddef>

#define NB 4
#define NS 4096
#define ND 2048
#define NH 16
#define NHD 128
#define NT 1024
#define NF 8192

typedef __bf16 bf16;
typedef __bf16 bf16x8 __attribute__((ext_vector_type(8)));
typedef __bf16 bf16x4 __attribute__((ext_vector_type(4)));
typedef float  f32x4  __attribute__((ext_vector_type(4)));

typedef const __attribute__((address_space(1))) void* gptr_t;
typedef __attribute__((address_space(3))) void* lptr_t;

__device__ __forceinline__ float wave_sum(float v) {
#pragma unroll
    for (int off = 32; off > 0; off >>= 1) v += __shfl_xor(v, off);
    return v;
}
__device__ __forceinline__ float wave_max(float v) {
#pragma unroll
    for (int off = 32; off > 0; off >>= 1) v = fmaxf(v, __shfl_xor(v, off));
    return v;
}

// ---------------------------------------------------------------------------
// Router + residual copy: logits[row] = dot(x[row,:], wr); out[row,:] = x[row,:]
// (x is streamed once; writing out here deletes the standalone copy kernel)
// ---------------------------------------------------------------------------
__global__ __launch_bounds__(256) void router_copy_k(const float* __restrict__ x,
                                                     const float* __restrict__ wr,
                                                     float* __restrict__ logits,
                                                     float4* __restrict__ out4) {
    __shared__ float r4[4];
    long long row = blockIdx.x;
    const float4* xr = (const float4*)(x + row * ND);
    float4* outr = out4 + row * (ND / 4);
    const float4* w4 = (const float4*)wr;
    float p = 0.f;
    for (int i = threadIdx.x; i < ND / 4; i += 256) {
        float4 a = xr[i], b = w4[i];
        outr[i] = a;
        p += a.x * b.x + a.y * b.y + a.z * b.z + a.w * b.w;
    }
    p = wave_sum(p);
    if ((threadIdx.x & 63) == 0) r4[threadIdx.x >> 6] = p;
    __syncthreads();
    if (threadIdx.x == 0) logits[row] = r4[0] + r4[1] + r4[2] + r4[3];
}

// ---------------------------------------------------------------------------
// Top-K (exact, matches jax.lax.top_k tie-break) + index sort + router softmax.
// ---------------------------------------------------------------------------
__global__ __launch_bounds__(1024) void topk_k(const float* __restrict__ logits,
                                               int* __restrict__ sel,
                                               float* __restrict__ rw) {
    __shared__ unsigned long long keys[NS];   // 32 KB
    __shared__ float r16[16];
    __shared__ float bmax, bsum;
    const int bb = blockIdx.x;
    const int tid = threadIdx.x;
    const float* lg = logits + (long long)bb * NS;

    for (int i = tid; i < NS; i += 1024) {
        unsigned u = __float_as_uint(lg[i]);
        u = (u & 0x80000000u) ? ~u : (u | 0x80000000u);   // order-preserving map
        keys[i] = ((unsigned long long)u << 32) | (unsigned)(NS - 1 - i);
    }
    __syncthreads();
    for (int k = 2; k <= NS; k <<= 1) {
        for (int j = k >> 1; j > 0; j >>= 1) {
            for (int i = tid; i < NS; i += 1024) {
                int ixj = i ^ j;
                if (ixj > i) {
                    unsigned long long a = keys[i], c = keys[ixj];
                    bool up = ((i & k) == 0);
                    if (up ? (a < c) : (a > c)) { keys[i] = c; keys[ixj] = a; }
                }
            }
            __syncthreads();
        }
    }
    unsigned long long a0 = keys[tid];
    __syncthreads();
    {
        unsigned idx_ = NS - 1 - (unsigned)(a0 & 0xFFFFFFFFu);
        unsigned uval = (unsigned)(a0 >> 32);
        keys[tid] = ((unsigned long long)idx_ << 32) | uval;
    }
    __syncthreads();
    for (int k = 2; k <= NT; k <<= 1) {
        for (int j = k >> 1; j > 0; j >>= 1) {
            int i = tid, ixj = i ^ j;
            if (i < NT && ixj > i) {
                unsigned long long a = keys[i], c = keys[ixj];
                bool up = ((i & k) == 0);
                if (up ? (a > c) : (a < c)) { keys[i] = c; keys[ixj] = a; }
            }
            __syncthreads();
        }
    }
    unsigned long long kk = keys[tid];
    int si = (int)(kk >> 32);
    unsigned u = (unsigned)(kk & 0xFFFFFFFFu);
    u = (u & 0x80000000u) ? (u ^ 0x80000000u) : ~u;
    float val = __uint_as_float(u);

    const int wid = tid >> 6, lane = tid & 63;
    float mx = wave_max(val);
    if (lane == 0) r16[wid] = mx;
    __syncthreads();
    if (tid == 0) {
        float m = r16[0];
        for (int i = 1; i < 16; i++) m = fmaxf(m, r16[i]);
        bmax = m;
    }
    __syncthreads();
    float e = __expf(val - bmax);
    float s = wave_sum(e);
    if (lane == 0) r16[wid] = s;
    __syncthreads();
    if (tid == 0) {
        float t = 0.f;
        for (int i = 0; i < 16; i++) t += r16[i];
        bsum = t;
    }
    __syncthreads();
    sel[bb * NT + tid] = si;
    rw[bb * NT + tid] = e / bsum;
}

// ---------------------------------------------------------------------------
// Fused gather + RMSNorm: row j reads x[b, sel[b,j], :] once, writes the
// raw row to xf (residual, consumed by MODE2/MODE5) and the normalized
// bf16 row to hbuf. Deletes the separate gather pass over xf.
// ---------------------------------------------------------------------------
__global__ __launch_bounds__(256) void gather_rms_k(const float* __restrict__ x,
                                                    const int* __restrict__ sel,
                                                    const float* __restrict__ g,
                                                    float* __restrict__ xf,
                                                    bf16* __restrict__ out) {
    __shared__ float r4[4];
    __shared__ float scl;
    long long row = blockIdx.x;               // [0, NB*NT)
    int bb = (int)(row >> 10);
    int s = sel[row];
    const float4* xr = (const float4*)(x + ((long long)bb * NS + s) * ND);
    float4* xfr = (float4*)(xf + row * ND);
    int i0 = threadIdx.x, i1 = threadIdx.x + 256;
    float4 a = xr[i0], b = xr[i1];
    xfr[i0] = a;
    xfr[i1] = b;
    float ss = a.x * a.x + a.y * a.y + a.z * a.z + a.w * a.w +
               b.x * b.x + b.y * b.y + b.z * b.z + b.w * b.w;
    ss = wave_sum(ss);
    if ((threadIdx.x & 63) == 0) r4[threadIdx.x >> 6] = ss;
    __syncthreads();
    if (threadIdx.x == 0)
        scl = rsqrtf((r4[0] + r4[1] + r4[2] + r4[3]) * (1.0f / ND) + 1e-6f);
    __syncthreads();
    float sc = scl;
    const float4* g4 = (const float4*)g;
    float4 ga = g4[i0], gb = g4[i1];
    bf16x4 o0, o1;
    o0[0] = (bf16)(a.x * sc * ga.x); o0[1] = (bf16)(a.y * sc * ga.y);
    o0[2] = (bf16)(a.z * sc * ga.z); o0[3] = (bf16)(a.w * sc * ga.w);
    o1[0] = (bf16)(b.x * sc * gb.x); o1[1] = (bf16)(b.y * sc * gb.y);
    o1[2] = (bf16)(b.z * sc * gb.z); o1[3] = (bf16)(b.w * sc * gb.w);
    *(bf16x4*)(out + row * ND + i0 * 4) = o0;
    *(bf16x4*)(out + row * ND + i1 * 4) = o1;
}

// ---------------------------------------------------------------------------
// RMSNorm row kernel: out = bf16(x * rsqrt(mean(x^2)+eps) * g)
// ---------------------------------------------------------------------------
__global__ __launch_bounds__(256) void rmsnorm_k(const float* __restrict__ x,
                                                 const float* __restrict__ g,
                                                 bf16* __restrict__ out) {
    __shared__ float r4[4];
    __shared__ float scl;
    long long row = blockIdx.x;
    const float4* xr = (const float4*)(x + row * ND);
    int i0 = threadIdx.x, i1 = threadIdx.x + 256;
    float4 a = xr[i0], b = xr[i1];
    float ss = a.x * a.x + a.y * a.y + a.z * a.z + a.w * a.w +
               b.x * b.x + b.y * b.y + b.z * b.z + b.w * b.w;
    ss = wave_sum(ss);
    if ((threadIdx.x & 63) == 0) r4[threadIdx.x >> 6] = ss;
    __syncthreads();
    if (threadIdx.x == 0)
        scl = rsqrtf((r4[0] + r4[1] + r4[2] + r4[3]) * (1.0f / ND) + 1e-6f);
    __syncthreads();
    float s = scl;
    const float4* g4 = (const float4*)g;
    float4 ga = g4[i0], gb = g4[i1];
    bf16x4 o0, o1;
    o0[0] = (bf16)(a.x * s * ga.x); o0[1] = (bf16)(a.y * s * ga.y);
    o0[2] = (bf16)(a.z * s * ga.z); o0[3] = (bf16)(a.w * s * ga.w);
    o1[0] = (bf16)(b.x * s * gb.x); o1[1] = (bf16)(b.y * s * gb.y);
    o1[2] = (bf16)(b.z * s * gb.z); o1[3] = (bf16)(b.w * s * gb.w);
    *(bf16x4*)(out + row * ND + i0 * 4) = o0;
    *(bf16x4*)(out + row * ND + i1 * 4) = o1;
}

// ---------------------------------------------------------------------------
// Transpose + fp32->bf16: out[c][r] = in[r][c]; in is R x C. dims %32 == 0.
// ---------------------------------------------------------------------------
__global__ __launch_bounds__(256) void transpose_to_bf16(const float* __restrict__ in,
                                                         bf16* __restrict__ out,
                                                         int R, int C) {
    __shared__ float tile[32][33];
    int bx = blockIdx.x * 32;   // col
    int by = blockIdx.y * 32;   // row
    int tx = threadIdx.x & 31;
    int ty = threadIdx.x >> 5;   // 0..7
#pragma unroll
    for (int i = 0; i < 4; i++)
        tile[ty + 8 * i][tx] = in[(long long)(by + ty + 8 * i) * C + bx + tx];
    __syncthreads();
#pragma unroll
    for (int i = 0; i < 4; i++)
        out[(long long)(bx + ty + 8 * i) * R + by + tx] = (bf16)tile[tx][ty + 8 * i];
}

// ---------------------------------------------------------------------------
// RoPE for Q,K only (reads fused QKV buffer, row stride 3*ND). Coalesced.
// ---------------------------------------------------------------------------
__global__ __launch_bounds__(256) void rope_qk_k(const bf16* __restrict__ QKV,
                                                 const float* __restrict__ fr,
                                                 bf16* __restrict__ Q,
                                                 bf16* __restrict__ K) {
    int gid = blockIdx.x * 256 + threadIdx.x;
    int hd = gid & 63;
    int h = (gid >> 6) & 15;
    int t = (gid >> 10) & (NT - 1);
    int bb = gid >> 20;
    float c = fr[t * 128 + hd * 2 + 0];
    float s = fr[t * 128 + hd * 2 + 1];
    long long base = ((long long)bb * NT + t) * (3 * ND) + h * NHD;
    float q1 = (float)QKV[base + hd],      q2 = (float)QKV[base + hd + 64];
    float k1 = (float)QKV[base + ND + hd], k2 = (float)QKV[base + ND + hd + 64];
    long long ob = (((long long)(bb * NH + h)) * NT + t) * NHD;
    Q[ob + hd]      = (bf16)(q1 * c - q2 * s);
    Q[ob + hd + 64] = (bf16)(q1 * s + q2 * c);
    K[ob + hd]      = (bf16)(k1 * c - k2 * s);
    K[ob + hd + 64] = (bf16)(k1 * s + k2 * c);
}

// ---------------------------------------------------------------------------
// V transpose via LDS tile: Vt[(b*16+h)][d][t] = QKV[b*NT+t][2*ND + h*128 + d].
// ---------------------------------------------------------------------------
__global__ __launch_bounds__(256) void vtr_k(const bf16* __restrict__ QKV,
                                             bf16* __restrict__ Vt) {
    __shared__ bf16 tile[64][136];   // padded: row stride 272B
    const int tt = blockIdx.x * 64;
    const int bh = blockIdx.y;
    const int bb = bh >> 4, h = bh & 15;
    const int tid = threadIdx.x;

    const int lt = tid >> 4;            // 0..15
    const int ld = (tid & 15) * 8;      // d-octet
#pragma unroll
    for (int i = 0; i < 4; i++) {
        int t = i * 16 + lt;
        bf16x8 v = *(const bf16x8*)(QKV + ((size_t)(bb * NT) + tt + t) * (3 * ND)
                                    + 2 * ND + h * NHD + ld);
        *(bf16x8*)&tile[t][ld] = v;
    }
    __syncthreads();

    const int d = tid >> 1;             // 0..127
    const int j0 = (tid & 1) * 32;      // t-half
    bf16 tmp[32];
#pragma unroll
    for (int j = 0; j < 32; j++) tmp[j] = tile[j0 + j][d];
    bf16* dst = Vt + ((size_t)bh * NHD + d) * NT + tt + j0;
#pragma unroll
    for (int j = 0; j < 4; j++)
        *(bf16x8*)(dst + j * 8) = *(const bf16x8*)(tmp + j * 8);
}

// ---------------------------------------------------------------------------
// Fused flash attention (non-causal, mask==0, S=1024, D=128).
// ---------------------------------------------------------------------------
__global__ __launch_bounds__(256, 2) void flash_k(
    const bf16* __restrict__ Qr,   // [(b*16+h)][t][128]
    const bf16* __restrict__ Kr,   // [(b*16+h)][t][128]
    const bf16* __restrict__ Vt,   // [(b*16+h)][d][1024]
    bf16* __restrict__ O) {        // [b*NT+t][ND], col h*128+d
    __shared__ char lds[81920];    // K: 2x16K @0, V: 2x16K @32768, P: 4x4K @65536

    const int tid = threadIdx.x;
    const int lane = tid & 63;
    const int w = tid >> 6;
    const int lm = lane & 15, lq = lane >> 4;
    const int lm7 = lm & 7;

    const int bh = blockIdx.y;
    const int q0 = blockIdx.x * 128;
    const bf16* Qb = Qr + (size_t)bh * NT * NHD;
    const bf16* Kb = Kr + (size_t)bh * NT * NHD;
    const bf16* Vb = Vt + (size_t)bh * NHD * NT;

    const int krow = tid >> 4;
    const int kc_s = (tid & 15);
    const int vrow = tid >> 3;
    const int vc_s = (tid & 7);

    bf16x8 q[2][4];
#pragma unroll
    for (int mi = 0; mi < 2; mi++)
#pragma unroll
        for (int ks = 0; ks < 4; ks++)
            q[mi][ks] = *(const bf16x8*)(Qb + (size_t)(q0 + w * 32 + mi * 16 + lm) * NHD
                                         + lq * 8 + ks * 32);

    f32x4 o0[8], o1[8];
#pragma unroll
    for (int i = 0; i < 8; i++) {
        f32x4 zz = {0.f, 0.f, 0.f, 0.f};
        o0[i] = zz; o1[i] = zz;
    }
    float m0[4], m1[4], l0[4], l1[4];
#pragma unroll
    for (int r = 0; r < 4; r++) {
        m0[r] = -3.0e38f; m1[r] = -3.0e38f; l0[r] = 0.f; l1[r] = 0.f;
    }

    char* Pb = lds + 65536 + w * 4096;
    const float kscal = 0.08838834764831845f * 1.4426950408889634f;

#pragma unroll
    for (int i = 0; i < 4; i++) {
        int row = i * 16 + krow;
        __builtin_amdgcn_global_load_lds(
            (gptr_t)(Kb + (size_t)row * NHD + (kc_s ^ (row & 7)) * 8),
            (lptr_t)(lds + i * 4096 + tid * 16), 16, 0, 0);
    }
#pragma unroll
    for (int i = 0; i < 4; i++) {
        int row = i * 32 + vrow;
        __builtin_amdgcn_global_load_lds(
            (gptr_t)(Vb + (size_t)row * NT + (vc_s ^ (row & 7)) * 8),
            (lptr_t)(lds + 32768 + i * 4096 + tid * 16), 16, 0, 0);
    }
    __syncthreads();

    for (int c = 0; c < 16; ++c) {
        char* Kl = lds + (c & 1) * 16384;
        char* Vl = lds + 32768 + (c & 1) * 16384;

        if (c < 15) {
            const int key1 = (c + 1) * 64;
            char* Kd = lds + ((c + 1) & 1) * 16384;
            char* Vd = lds + 32768 + ((c + 1) & 1) * 16384;
#pragma unroll
            for (int i = 0; i < 4; i++) {
                int row = i * 16 + krow;
                __builtin_amdgcn_global_load_lds(
                    (gptr_t)(Kb + (size_t)(key1 + row) * NHD + (kc_s ^ (row & 7)) * 8),
                    (lptr_t)(Kd + i * 4096 + tid * 16), 16, 0, 0);
            }
#pragma unroll
            for (int i = 0; i < 4; i++) {
                int row = i * 32 + vrow;
                __builtin_amdgcn_global_load_lds(
                    (gptr_t)(Vb + (size_t)row * NT + key1 + (vc_s ^ (row & 7)) * 8),
                    (lptr_t)(Vd + i * 4096 + tid * 16), 16, 0, 0);
            }
        }

        // ---- QK^T ----
        f32x4 s0[4], s1[4];
#pragma unroll
        for (int ni = 0; ni < 4; ni++) {
            f32x4 zz = {0.f, 0.f, 0.f, 0.f};
            s0[ni] = zz; s1[ni] = zz;
        }
        __builtin_amdgcn_s_setprio(1);
#pragma unroll
        for (int ni = 0; ni < 4; ni++) {
#pragma unroll
            for (int ks = 0; ks < 4; ks++) {
                bf16x8 kf = *(const bf16x8*)(Kl + (lm + 16 * ni) * 256
                                             + (((lq + 4 * ks) ^ lm7) << 4));
                s0[ni] = __builtin_amdgcn_mfma_f32_16x16x32_bf16(q[0][ks], kf, s0[ni], 0, 0, 0);
                s1[ni] = __builtin_amdgcn_mfma_f32_16x16x32_bf16(q[1][ks], kf, s1[ni], 0, 0, 0);
            }
        }
        __builtin_amdgcn_s_setprio(0);

#pragma unroll
        for (int ni = 0; ni < 4; ni++)
#pragma unroll
            for (int r = 0; r < 4; r++) {
                s0[ni][r] *= kscal;
                s1[ni][r] *= kscal;
            }

        float sc0[4], sc1[4];
#pragma unroll
        for (int r = 0; r < 4; r++) {
            float a0 = fmaxf(fmaxf(s0[0][r], s0[1][r]), fmaxf(s0[2][r], s0[3][r]));
            float a1 = fmaxf(fmaxf(s1[0][r], s1[1][r]), fmaxf(s1[2][r], s1[3][r]));
#pragma unroll
            for (int o = 1; o < 16; o <<= 1) {
                a0 = fmaxf(a0, __shfl_xor(a0, o));
                a1 = fmaxf(a1, __shfl_xor(a1, o));
            }
            float mn0 = fmaxf(m0[r], a0);
            float mn1 = fmaxf(m1[r], a1);
            sc0[r] = exp2f(m0[r] - mn0);
            sc1[r] = exp2f(m1[r] - mn1);
            m0[r] = mn0; m1[r] = mn1;

            float rs0 = 0.f, rs1 = 0.f;
#pragma unroll
            for (int ni = 0; ni < 4; ni++) {
                float p0 = exp2f(s0[ni][r] - mn0);
                float p1 = exp2f(s1[ni][r] - mn1);
                s0[ni][r] = p0; s1[ni][r] = p1;
                rs0 += p0; rs1 += p1;
            }
#pragma unroll
            for (int o = 1; o < 16; o <<= 1) {
                rs0 += __shfl_xor(rs0, o);
                rs1 += __shfl_xor(rs1, o);
            }
            l0[r] = l0[r] * sc0[r] + rs0;
            l1[r] = l1[r] * sc1[r] + rs1;
        }
#pragma unroll
        for (int ni = 0; ni < 8; ni++)
#pragma unroll
            for (int r = 0; r < 4; r++) {
                o0[ni][r] *= sc0[r];
                o1[ni][r] *= sc1[r];
            }

#pragma unroll
        for (int ni = 0; ni < 4; ni++)
#pragma unroll
            for (int r = 0; r < 4; r++) {
                int q_l0 = lq * 4 + r;
                int q_l1 = 16 + q_l0;
                int cw = (lm >> 3) + 2 * ni;
                *(bf16*)(Pb + q_l0 * 128 + ((cw ^ (q_l0 & 7)) << 4) + (lm7 << 1)) =
                    (bf16)s0[ni][r];
                *(bf16*)(Pb + q_l1 * 128 + ((cw ^ (q_l1 & 7)) << 4) + (lm7 << 1)) =
                    (bf16)s1[ni][r];
            }
        asm volatile("s_waitcnt lgkmcnt(0)" ::: "memory");
        __builtin_amdgcn_sched_barrier(0);

        __builtin_amdgcn_s_setprio(1);
#pragma unroll
        for (int ks = 0; ks < 2; ks++) {
            bf16x8 pa0 = *(const bf16x8*)(Pb + lm * 128 + (((lq + 4 * ks) ^ lm7) << 4));
            bf16x8 pa1 = *(const bf16x8*)(Pb + (lm + 16) * 128 + (((lq + 4 * ks) ^ lm7) << 4));
#pragma unroll
            for (int ni = 0; ni < 8; ni++) {
                bf16x8 vf = *(const bf16x8*)(Vl + (lm + 16 * ni) * 128
                                             + (((lq + 4 * ks) ^ lm7) << 4));
                o0[ni] = __builtin_amdgcn_mfma_f32_16x16x32_bf16(pa0, vf, o0[ni], 0, 0, 0);
                o1[ni] = __builtin_amdgcn_mfma_f32_16x16x32_bf16(pa1, vf, o1[ni], 0, 0, 0);
            }
        }
        __builtin_amdgcn_s_setprio(0);

        __syncthreads();
    }

    const int bb = bh >> 4, h = bh & 15;
    float rl0[4], rl1[4];
#pragma unroll
    for (int r = 0; r < 4; r++) { rl0[r] = 1.f / l0[r]; rl1[r] = 1.f / l1[r]; }
#pragma unroll
    for (int ni = 0; ni < 8; ni++) {
#pragma unroll
        for (int r = 0; r < 4; r++) {
            int col = h * 128 + lm + 16 * ni;
            long long r0 = (long long)bb * NT + q0 + w * 32 + lq * 4 + r;
            O[(r0) * ND + col]      = (bf16)(o0[ni][r] * rl0[r]);
            O[(r0 + 16) * ND + col] = (bf16)(o1[ni][r] * rl1[r]);
        }
    }
}

// ---------------------------------------------------------------------------
// 256xN pipelined GEMM (r7 version: BK=64, counted-lgkmcnt, 2 barriers/K-tile).
//   NTILE=256 (MODE 0/6): 24 reads, 8 gloads/tile, LDS 128K.
//   NTILE=128 (MODE 2/5): 20 reads, 6 gloads/tile, LDS 96K; non-atomic
//   epilogues (exclusive tiles).
// MODE 0: C bf16 = alpha*acc          MODE 2: C fp32 += acc (exclusive)
// MODE 5: out[(b*NS+sel[m])*ND+n] += rw[m]*(acc+res)   (exclusive)
// MODE 6: dual-B (w1,w3): C bf16 = silu(acc1)*acc3
// ---------------------------------------------------------------------------
#define G256_SB() __builtin_amdgcn_sched_barrier(0)
#define G256_LGKM(n) do { asm volatile("s_waitcnt lgkmcnt(" #n ")" ::: "memory"); \
    __builtin_amdgcn_sched_barrier(0); } while (0)
#define G256_VMC(n) do { asm volatile("s_waitcnt vmcnt(" #n ")" ::: "memory"); \
    __builtin_amdgcn_sched_barrier(0); } while (0)

#define MFMA_Q(mlo, nlo) do { \
    __builtin_amdgcn_s_setprio(1); \
    _Pragma("unroll") \
    for (int _ks = 0; _ks < 2; _ks++) \
    _Pragma("unroll") \
    for (int _mi = 0; _mi < 4; _mi++) \
    _Pragma("unroll") \
    for (int _ni = 0; _ni < 2; _ni++) \
        acc[(mlo) + _mi][(nlo) + _ni] = __builtin_amdgcn_mfma_f32_16x16x32_bf16( \
            a[(mlo) + _mi][_ks], b[(nlo) + _ni][_ks], acc[(mlo) + _mi][(nlo) + _ni], \
            0, 0, 0); \
    __builtin_amdgcn_s_setprio(0); \
} while (0)

template <int MODE>
__global__ __launch_bounds__(512, 2) void gemm256(
    const bf16* __restrict__ A, int lda,
    const bf16* __restrict__ Bt, int ldb,
    void* __restrict__ Cv, int ldc,
    int K, float alpha,
    const bf16* __restrict__ Bt2,
    const float* __restrict__ res, const int* __restrict__ selp,
    const float* __restrict__ rwp, float* __restrict__ outp) {

    constexpr bool DUALB = (MODE == 6);
    constexpr bool N128  = (MODE == 2 || MODE == 5);
    constexpr bool NI4   = !N128;                    // 4 B-frag pairs
    constexpr int  BBUF  = N128 ? 16384 : 32768;     // B bytes per buffer
    constexpr int  BUFS  = 32768 + BBUF;             // per-buffer bytes
    constexpr int  bw    = (DUALB || N128) ? 32 : 64;   // cols per wave
    constexpr int  bStep2 = DUALB ? 16384 : 4096;    // ni-pair 1 byte offset
    constexpr int  NIE   = (DUALB || N128) ? 2 : 4;  // epilogue ni count
    __shared__ char smem[2 * BUFS];

    const int tid = threadIdx.x;
    const int lane = tid & 63;
    const int wid = tid >> 6;
    const int wm = wid >> 2, wn = wid & 3;     // 2 x 4 waves
    const int lm = lane & 15, lq = lane >> 4;

    // 2D XCD mapping: xcd quadrant (2M x 4N), 8 x (nx/4) rect inside, M-first.
    // Requires ny==16, nx%4==0.
    const int nx = gridDim.x;
    const int orig = blockIdx.y * nx + blockIdx.x;
    const int xcd = orig & 7;
    const int r_ = orig >> 3;
    const int mi_ = r_ & 7, ni_ = r_ >> 3;
    const int nT = (DUALB || N128) ? 128 : 256;
    const int m0 = ((xcd >> 2) * 8 + mi_) * 256;
    const int n0 = ((xcd & 3) * (nx >> 2) + ni_) * nT;
    const long long kz = (long long)blockIdx.z * K;

    // staging: thread stages 16B chunk; LDS linear, global source pre-swizzled
    const int srow = tid >> 3;                 // [0,64)
    const int skc = ((tid & 7) ^ (srow & 7)) * 8;
    const long long stA = (long long)64 * lda;
    const long long stB = (long long)64 * ldb;
    const bf16* gA = A + (long long)(m0 + srow) * lda + kz + skc;
    const bf16* gB0 = Bt + (long long)(n0 + srow) * ldb + kz + skc;
    const bf16* gB2 = DUALB ? Bt2 + (long long)(n0 + srow) * ldb + kz + skc
                            : gB0 + 2 * stB;

    char* sm = (char*)smem;
    const int sdst = tid * 16;

    auto stage = [&](int c, int t) {
        char* lA = sm + c * BUFS + sdst;
        long long ko = (long long)t * 64;
#pragma unroll
        for (int i = 0; i < 4; i++)
            __builtin_amdgcn_global_load_lds((gptr_t)(gA + i * stA + ko),
                                             (lptr_t)(lA + i * 8192), 16, 0, 0);
        char* lB = sm + c * BUFS + 32768 + sdst;
        __builtin_amdgcn_global_load_lds((gptr_t)(gB0 + ko), (lptr_t)lB, 16, 0, 0);
        __builtin_amdgcn_global_load_lds((gptr_t)(gB0 + stB + ko),
                                         (lptr_t)(lB + 8192), 16, 0, 0);
        if constexpr (NI4) {
            __builtin_amdgcn_global_load_lds((gptr_t)(gB2 + ko),
                                             (lptr_t)(lB + 16384), 16, 0, 0);
            __builtin_amdgcn_global_load_lds((gptr_t)(gB2 + stB + ko),
                                             (lptr_t)(lB + 24576), 16, 0, 0);
        }
    };

    // frag read offsets: row*128 + ((ks*4+lq) ^ (lm&7))*16 ; ks=1 is ^64
    const int aoff = (wm * 128 + lm) * 128 + ((lq ^ (lm & 7)) << 4);
    const int boff = (wn * bw + lm) * 128 + ((lq ^ (lm & 7)) << 4);

    f32x4 acc[8][4];
#pragma unroll
    for (int i = 0; i < 8; i++)
#pragma unroll
        for (int j = 0; j < 4; j++) {
            f32x4 zz = {0.f, 0.f, 0.f, 0.f};
            acc[i][j] = zz;
        }
    bf16x8 a[8][2], b[4][2];

    auto ldA4 = [&](char* bA, int lo) {
#pragma unroll
        for (int mi2 = 0; mi2 < 4; mi2++) {
            a[lo + mi2][0] = *(const bf16x8*)(bA + aoff + (lo + mi2) * 2048);
            a[lo + mi2][1] = *(const bf16x8*)(bA + (aoff ^ 64) + (lo + mi2) * 2048);
        }
    };
    auto ldB2 = [&](char* bB, int lo) {
#pragma unroll
        for (int ni2 = 0; ni2 < 2; ni2++) {
            int ix = lo + ni2;
            int o = boff + (ix & 1) * 2048 + (ix >> 1) * bStep2;
            b[ix][0] = *(const bf16x8*)(bB + o);
            b[ix][1] = *(const bf16x8*)(bB + (o ^ 64));
        }
    };

    const int NTk = K >> 6;

    // prologue: stage tile0 -> buf0, tile1 -> buf1; wait tile0
    stage(0, 0);
    stage(1, 1);
    if constexpr (NI4) { G256_VMC(8); } else { G256_VMC(6); }
    __builtin_amdgcn_s_barrier();
    G256_SB();

    for (int t = 0; t < NTk; ++t) {
        const int c = t & 1;
        char* bA = sm + c * BUFS;
        char* bB = bA + 32768;

        // issue all frag reads; group order pinned (counts depend on it)
        ldA4(bA, 0);
        ldB2(bB, 0);           // group1: 12 reads
        G256_SB();
        if constexpr (NI4) {
            ldB2(bB, 2);       // group2: 4 reads
            G256_SB();
        }
        ldA4(bA, 4);           // group3: 8 reads
        G256_SB();

        if constexpr (NI4) { G256_LGKM(12); } else { G256_LGKM(8); }
        MFMA_Q(0, 0);
        if constexpr (NI4) {
            G256_LGKM(8);
            MFMA_Q(0, 2);
        }
        G256_LGKM(0);                        // all reads of buf c done
        __builtin_amdgcn_s_barrier();        // release buf c
        G256_SB();
        const bool more = (t + 2 < NTk);
        if (more) stage(c, t + 2);           // overwrite buf c with t+2
        G256_SB();
        MFMA_Q(4, 0);                        // overlaps staging
        if constexpr (NI4) MFMA_Q(4, 2);
        if (more) {
            if constexpr (NI4) { G256_VMC(8); } else { G256_VMC(6); }
        } else {
            G256_VMC(0);
        }
        __builtin_amdgcn_s_barrier();        // buf c^1 (tile t+1) visible
        G256_SB();
    }

    if constexpr (MODE == 6) {
        bf16* C = (bf16*)Cv;
#pragma unroll
        for (int mi = 0; mi < 8; mi++) {
#pragma unroll
            for (int ni = 0; ni < 2; ni++) {
                const int row = m0 + wm * 128 + mi * 16 + lq * 4;
                const int col = n0 + wn * 32 + ni * 16 + lm;
#pragma unroll
                for (int r = 0; r < 4; r++) {
                    float v1 = acc[mi][ni][r];
                    float v3 = acc[mi][ni + 2][r];
                    C[(long long)(row + r) * ldc + col] =
                        (bf16)((v1 / (1.f + __expf(-v1))) * v3);
                }
            }
        }
    } else {
#pragma unroll
        for (int mi = 0; mi < 8; mi++) {
#pragma unroll
            for (int ni = 0; ni < NIE; ni++) {
                const int row = m0 + wm * 128 + mi * 16 + lq * 4;
                const int col = n0 + wn * bw + ni * 16 + lm;
#pragma unroll
                for (int r = 0; r < 4; r++) {
                    float v = alpha * acc[mi][ni][r];
                    long long rr = row + r;
                    if constexpr (MODE == 0) {
                        bf16* C = (bf16*)Cv;
                        C[rr * ldc + col] = (bf16)v;
                    } else if constexpr (MODE == 2) {
                        float* C = (float*)Cv;
                        C[rr * ldc + col] += v;       // exclusive tile
                    } else {   // MODE 5
                        int bb2 = (int)(rr >> 10);
                        int s = selp[rr];
                        float add = rwp[rr] * (v + res[rr * (long long)ND + col]);
                        outp[((long long)bb2 * NS + s) * ND + col] += add;  // exclusive
                    }
                }
            }
        }
    }
}

// ---------------------------------------------------------------------------
extern "C" void kernel_launch(void* const* d_in, const int* in_sizes, int n_in,
                              void* d_out, int out_size, void* d_ws, size_t ws_size,
                              hipStream_t stream) {
    const float* x  = (const float*)d_in[0];
    const float* fr = (const float*)d_in[2];
    const float* wr = (const float*)d_in[3];
    const float* g1 = (const float*)d_in[4];
    const float* wq = (const float*)d_in[5];
    const float* wk = (const float*)d_in[6];
    const float* wv = (const float*)d_in[7];
    const float* wo = (const float*)d_in[8];
    const float* g2 = (const float*)d_in[9];
    const float* w1 = (const float*)d_in[10];
    const float* w3 = (const float*)d_in[11];
    const float* w2 = (const float*)d_in[12];
    float* out = (float*)d_out;

    char* ws = (char*)d_ws;
    size_t off = 0;
    auto take = [&](size_t bytes) -> char* {
        char* p = ws + off;
        off += (bytes + 255) & ~(size_t)255;
        return p;
    };
    int*   sel    = (int*)take((size_t)NB * NT * 4);
    float* rw     = (float*)take((size_t)NB * NT * 4);
    float* logits = (float*)take((size_t)NB * NS * 4);
    float* xf     = (float*)take((size_t)NB * NT * ND * 4);
    bf16*  hbuf   = (bf16*)take((size_t)NB * NT * ND * 2);
    bf16*  wqkv_t = (bf16*)take((size_t)3 * ND * ND * 2);
    bf16*  wo_t   = (bf16*)take((size_t)ND * ND * 2);
    bf16*  Obuf   = (bf16*)take((size_t)NB * NT * ND * 2);
    char* xr = ws + off;
    // attention-phase overlay
    bf16* QKV = (bf16*)xr;                               // [4096][6144]
    bf16* Qr  = QKV + (size_t)NB * NT * 3 * ND;
    bf16* Kr  = Qr + (size_t)NB * NT * ND;
    bf16* Vt  = Kr + (size_t)NB * NT * ND;
    // FFN-phase overlay (attention data dead by then)
    bf16* w1_t  = (bf16*)xr;
    bf16* w3_t  = w1_t + (size_t)ND * NF;
    bf16* w2_t  = w3_t + (size_t)ND * NF;
    bf16* inter = w2_t + (size_t)ND * NF;

    // router + out = x copy fused (x streamed once)
    router_copy_k<<<NB * NS, 256, 0, stream>>>(x, wr, logits, (float4*)out);
    topk_k<<<NB, 1024, 0, stream>>>(logits, sel, rw);
    // gather + rmsnorm #1 fused (writes xf residual + normalized hbuf)
    gather_rms_k<<<NB * NT, 256, 0, stream>>>(x, sel, g1, xf, hbuf);

    dim3 tg(ND / 32, ND / 32);
    transpose_to_bf16<<<tg, 256, 0, stream>>>(wq, wqkv_t, ND, ND);
    transpose_to_bf16<<<tg, 256, 0, stream>>>(wk, wqkv_t + (size_t)ND * ND, ND, ND);
    transpose_to_bf16<<<tg, 256, 0, stream>>>(wv, wqkv_t + (size_t)2 * ND * ND, ND, ND);
    transpose_to_bf16<<<tg, 256, 0, stream>>>(wo, wo_t, ND, ND);

    // fused QKV: [4096 x 2048] x [6144 x 2048]^T -> [4096][6144]
    gemm256<0><<<dim3(3 * ND / 256, NB * NT / 256, 1), 512, 0, stream>>>(
        hbuf, ND, wqkv_t, ND, QKV, 3 * ND, ND, 1.0f,
        nullptr, nullptr, nullptr, nullptr, nullptr);

    rope_qk_k<<<(NB * NT * NH * 64) / 256, 256, 0, stream>>>(QKV, fr, Qr, Kr);
    vtr_k<<<dim3(NT / 64, NB * NH), 256, 0, stream>>>(QKV, Vt);

    // fused flash attention
    flash_k<<<dim3(NT / 128, NB * NH), 256, 0, stream>>>(Qr, Kr, Vt, Obuf);

    // WO: 128-N tiles, single-z, non-atomic += into xf residual
    gemm256<2><<<dim3(ND / 128, NB * NT / 256, 1), 512, 0, stream>>>(
        Obuf, ND, wo_t, ND, xf, ND, ND, 1.0f,
        nullptr, nullptr, nullptr, nullptr, nullptr);

    rmsnorm_k<<<NB * NT, 256, 0, stream>>>(xf, g2, hbuf);

    transpose_to_bf16<<<dim3(NF / 32, ND / 32), 256, 0, stream>>>(w1, w1_t, ND, NF);
    transpose_to_bf16<<<dim3(NF / 32, ND / 32), 256, 0, stream>>>(w3, w3_t, ND, NF);
    transpose_to_bf16<<<dim3(ND / 32, NF / 32), 256, 0, stream>>>(w2, w2_t, NF, ND);

    // fused FFN up: inter = silu(h.w1) * (h.w3)
    gemm256<6><<<dim3(NF / 128, NB * NT / 256, 1), 512, 0, stream>>>(
        hbuf, ND, w1_t, ND, inter, NF, ND, 1.0f,
        w3_t, nullptr, nullptr, nullptr, nullptr);

    // w2 + scatter-add: 128-N tiles, single-z, non-atomic (tiles exclusive)
    gemm256<5><<<dim3(ND / 128, NB * NT / 256, 1), 512, 0, stream>>>(
        inter, NF, w2_t, NF, nullptr, ND, NF, 1.0f,
        nullptr, xf, sel, rw, out);
}

// Round 14
// 1190.266 us; speedup vs baseline: 1.3662x; 1.0020x over previous
//
#include <hip/hip_runtime.h>
#include <cstdint>
#include <cstddef>

#define NB 4
#define NS 4096
#define ND 2048
#define NH 16
#define NHD 128
#define NT 1024
#define NF 8192

typedef __bf16 bf16;
typedef __bf16 bf16x8 __attribute__((ext_vector_type(8)));
typedef __bf16 bf16x4 __attribute__((ext_vector_type(4)));
typedef float  f32x4  __attribute__((ext_vector_type(4)));

typedef const __attribute__((address_space(1))) void* gptr_t;
typedef __attribute__((address_space(3))) void* lptr_t;

__device__ __forceinline__ float wave_sum(float v) {
#pragma unroll
    for (int off = 32; off > 0; off >>= 1) v += __shfl_xor(v, off);
    return v;
}
__device__ __forceinline__ float wave_max(float v) {
#pragma unroll
    for (int off = 32; off > 0; off >>= 1) v = fmaxf(v, __shfl_xor(v, off));
    return v;
}

// ---------------------------------------------------------------------------
// Router + residual copy: logits[row] = dot(x[row,:], wr); out[row,:] = x[row,:]
// (x is streamed once; writing out here deletes the standalone copy kernel)
// ---------------------------------------------------------------------------
__global__ __launch_bounds__(256) void router_copy_k(const float* __restrict__ x,
                                                     const float* __restrict__ wr,
                                                     float* __restrict__ logits,
                                                     float4* __restrict__ out4) {
    __shared__ float r4[4];
    long long row = blockIdx.x;
    const float4* xr = (const float4*)(x + row * ND);
    float4* outr = out4 + row * (ND / 4);
    const float4* w4 = (const float4*)wr;
    float p = 0.f;
    for (int i = threadIdx.x; i < ND / 4; i += 256) {
        float4 a = xr[i], b = w4[i];
        outr[i] = a;
        p += a.x * b.x + a.y * b.y + a.z * b.z + a.w * b.w;
    }
    p = wave_sum(p);
    if ((threadIdx.x & 63) == 0) r4[threadIdx.x >> 6] = p;
    __syncthreads();
    if (threadIdx.x == 0) logits[row] = r4[0] + r4[1] + r4[2] + r4[3];
}

// ---------------------------------------------------------------------------
// Top-K (exact, matches jax.lax.top_k tie-break) + index sort + router softmax.
// ---------------------------------------------------------------------------
__global__ __launch_bounds__(1024) void topk_k(const float* __restrict__ logits,
                                               int* __restrict__ sel,
                                               float* __restrict__ rw) {
    __shared__ unsigned long long keys[NS];   // 32 KB
    __shared__ float r16[16];
    __shared__ float bmax, bsum;
    const int bb = blockIdx.x;
    const int tid = threadIdx.x;
    const float* lg = logits + (long long)bb * NS;

    for (int i = tid; i < NS; i += 1024) {
        unsigned u = __float_as_uint(lg[i]);
        u = (u & 0x80000000u) ? ~u : (u | 0x80000000u);   // order-preserving map
        keys[i] = ((unsigned long long)u << 32) | (unsigned)(NS - 1 - i);
    }
    __syncthreads();
    for (int k = 2; k <= NS; k <<= 1) {
        for (int j = k >> 1; j > 0; j >>= 1) {
            for (int i = tid; i < NS; i += 1024) {
                int ixj = i ^ j;
                if (ixj > i) {
                    unsigned long long a = keys[i], c = keys[ixj];
                    bool up = ((i & k) == 0);
                    if (up ? (a < c) : (a > c)) { keys[i] = c; keys[ixj] = a; }
                }
            }
            __syncthreads();
        }
    }
    unsigned long long a0 = keys[tid];
    __syncthreads();
    {
        unsigned idx_ = NS - 1 - (unsigned)(a0 & 0xFFFFFFFFu);
        unsigned uval = (unsigned)(a0 >> 32);
        keys[tid] = ((unsigned long long)idx_ << 32) | uval;
    }
    __syncthreads();
    for (int k = 2; k <= NT; k <<= 1) {
        for (int j = k >> 1; j > 0; j >>= 1) {
            int i = tid, ixj = i ^ j;
            if (i < NT && ixj > i) {
                unsigned long long a = keys[i], c = keys[ixj];
                bool up = ((i & k) == 0);
                if (up ? (a > c) : (a < c)) { keys[i] = c; keys[ixj] = a; }
            }
            __syncthreads();
        }
    }
    unsigned long long kk = keys[tid];
    int si = (int)(kk >> 32);
    unsigned u = (unsigned)(kk & 0xFFFFFFFFu);
    u = (u & 0x80000000u) ? (u ^ 0x80000000u) : ~u;
    float val = __uint_as_float(u);

    const int wid = tid >> 6, lane = tid & 63;
    float mx = wave_max(val);
    if (lane == 0) r16[wid] = mx;
    __syncthreads();
    if (tid == 0) {
        float m = r16[0];
        for (int i = 1; i < 16; i++) m = fmaxf(m, r16[i]);
        bmax = m;
    }
    __syncthreads();
    float e = __expf(val - bmax);
    float s = wave_sum(e);
    if (lane == 0) r16[wid] = s;
    __syncthreads();
    if (tid == 0) {
        float t = 0.f;
        for (int i = 0; i < 16; i++) t += r16[i];
        bsum = t;
    }
    __syncthreads();
    sel[bb * NT + tid] = si;
    rw[bb * NT + tid] = e / bsum;
}

// ---------------------------------------------------------------------------
// Fused gather + RMSNorm: row j reads x[b, sel[b,j], :] once, writes the
// raw row to xf (residual, consumed by MODE2/MODE5) and the normalized
// bf16 row to hbuf. Deletes the separate gather pass over xf.
// ---------------------------------------------------------------------------
__global__ __launch_bounds__(256) void gather_rms_k(const float* __restrict__ x,
                                                    const int* __restrict__ sel,
                                                    const float* __restrict__ g,
                                                    float* __restrict__ xf,
                                                    bf16* __restrict__ out) {
    __shared__ float r4[4];
    __shared__ float scl;
    long long row = blockIdx.x;               // [0, NB*NT)
    int bb = (int)(row >> 10);
    int s = sel[row];
    const float4* xr = (const float4*)(x + ((long long)bb * NS + s) * ND);
    float4* xfr = (float4*)(xf + row * ND);
    int i0 = threadIdx.x, i1 = threadIdx.x + 256;
    float4 a = xr[i0], b = xr[i1];
    xfr[i0] = a;
    xfr[i1] = b;
    float ss = a.x * a.x + a.y * a.y + a.z * a.z + a.w * a.w +
               b.x * b.x + b.y * b.y + b.z * b.z + b.w * b.w;
    ss = wave_sum(ss);
    if ((threadIdx.x & 63) == 0) r4[threadIdx.x >> 6] = ss;
    __syncthreads();
    if (threadIdx.x == 0)
        scl = rsqrtf((r4[0] + r4[1] + r4[2] + r4[3]) * (1.0f / ND) + 1e-6f);
    __syncthreads();
    float sc = scl;
    const float4* g4 = (const float4*)g;
    float4 ga = g4[i0], gb = g4[i1];
    bf16x4 o0, o1;
    o0[0] = (bf16)(a.x * sc * ga.x); o0[1] = (bf16)(a.y * sc * ga.y);
    o0[2] = (bf16)(a.z * sc * ga.z); o0[3] = (bf16)(a.w * sc * ga.w);
    o1[0] = (bf16)(b.x * sc * gb.x); o1[1] = (bf16)(b.y * sc * gb.y);
    o1[2] = (bf16)(b.z * sc * gb.z); o1[3] = (bf16)(b.w * sc * gb.w);
    *(bf16x4*)(out + row * ND + i0 * 4) = o0;
    *(bf16x4*)(out + row * ND + i1 * 4) = o1;
}

// ---------------------------------------------------------------------------
// RMSNorm row kernel: out = bf16(x * rsqrt(mean(x^2)+eps) * g)
// ---------------------------------------------------------------------------
__global__ __launch_bounds__(256) void rmsnorm_k(const float* __restrict__ x,
                                                 const float* __restrict__ g,
                                                 bf16* __restrict__ out) {
    __shared__ float r4[4];
    __shared__ float scl;
    long long row = blockIdx.x;
    const float4* xr = (const float4*)(x + row * ND);
    int i0 = threadIdx.x, i1 = threadIdx.x + 256;
    float4 a = xr[i0], b = xr[i1];
    float ss = a.x * a.x + a.y * a.y + a.z * a.z + a.w * a.w +
               b.x * b.x + b.y * b.y + b.z * b.z + b.w * b.w;
    ss = wave_sum(ss);
    if ((threadIdx.x & 63) == 0) r4[threadIdx.x >> 6] = ss;
    __syncthreads();
    if (threadIdx.x == 0)
        scl = rsqrtf((r4[0] + r4[1] + r4[2] + r4[3]) * (1.0f / ND) + 1e-6f);
    __syncthreads();
    float s = scl;
    const float4* g4 = (const float4*)g;
    float4 ga = g4[i0], gb = g4[i1];
    bf16x4 o0, o1;
    o0[0] = (bf16)(a.x * s * ga.x); o0[1] = (bf16)(a.y * s * ga.y);
    o0[2] = (bf16)(a.z * s * ga.z); o0[3] = (bf16)(a.w * s * ga.w);
    o1[0] = (bf16)(b.x * s * gb.x); o1[1] = (bf16)(b.y * s * gb.y);
    o1[2] = (bf16)(b.z * s * gb.z); o1[3] = (bf16)(b.w * s * gb.w);
    *(bf16x4*)(out + row * ND + i0 * 4) = o0;
    *(bf16x4*)(out + row * ND + i1 * 4) = o1;
}

// ---------------------------------------------------------------------------
// Transpose + fp32->bf16: out[c][r] = in[r][c]; in is R x C. dims %32 == 0.
// ---------------------------------------------------------------------------
__global__ __launch_bounds__(256) void transpose_to_bf16(const float* __restrict__ in,
                                                         bf16* __restrict__ out,
                                                         int R, int C) {
    __shared__ float tile[32][33];
    int bx = blockIdx.x * 32;   // col
    int by = blockIdx.y * 32;   // row
    int tx = threadIdx.x & 31;
    int ty = threadIdx.x >> 5;   // 0..7
#pragma unroll
    for (int i = 0; i < 4; i++)
        tile[ty + 8 * i][tx] = in[(long long)(by + ty + 8 * i) * C + bx + tx];
    __syncthreads();
#pragma unroll
    for (int i = 0; i < 4; i++)
        out[(long long)(bx + ty + 8 * i) * R + by + tx] = (bf16)tile[tx][ty + 8 * i];
}

// ---------------------------------------------------------------------------
// RoPE for Q,K only (reads fused QKV buffer, row stride 3*ND). Coalesced.
// ---------------------------------------------------------------------------
__global__ __launch_bounds__(256) void rope_qk_k(const bf16* __restrict__ QKV,
                                                 const float* __restrict__ fr,
                                                 bf16* __restrict__ Q,
                                                 bf16* __restrict__ K) {
    int gid = blockIdx.x * 256 + threadIdx.x;
    int hd = gid & 63;
    int h = (gid >> 6) & 15;
    int t = (gid >> 10) & (NT - 1);
    int bb = gid >> 20;
    float c = fr[t * 128 + hd * 2 + 0];
    float s = fr[t * 128 + hd * 2 + 1];
    long long base = ((long long)bb * NT + t) * (3 * ND) + h * NHD;
    float q1 = (float)QKV[base + hd],      q2 = (float)QKV[base + hd + 64];
    float k1 = (float)QKV[base + ND + hd], k2 = (float)QKV[base + ND + hd + 64];
    long long ob = (((long long)(bb * NH + h)) * NT + t) * NHD;
    Q[ob + hd]      = (bf16)(q1 * c - q2 * s);
    Q[ob + hd + 64] = (bf16)(q1 * s + q2 * c);
    K[ob + hd]      = (bf16)(k1 * c - k2 * s);
    K[ob + hd + 64] = (bf16)(k1 * s + k2 * c);
}

// ---------------------------------------------------------------------------
// V transpose via LDS tile: Vt[(b*16+h)][d][t] = QKV[b*NT+t][2*ND + h*128 + d].
// ---------------------------------------------------------------------------
__global__ __launch_bounds__(256) void vtr_k(const bf16* __restrict__ QKV,
                                             bf16* __restrict__ Vt) {
    __shared__ bf16 tile[64][136];   // padded: row stride 272B
    const int tt = blockIdx.x * 64;
    const int bh = blockIdx.y;
    const int bb = bh >> 4, h = bh & 15;
    const int tid = threadIdx.x;

    const int lt = tid >> 4;            // 0..15
    const int ld = (tid & 15) * 8;      // d-octet
#pragma unroll
    for (int i = 0; i < 4; i++) {
        int t = i * 16 + lt;
        bf16x8 v = *(const bf16x8*)(QKV + ((size_t)(bb * NT) + tt + t) * (3 * ND)
                                    + 2 * ND + h * NHD + ld);
        *(bf16x8*)&tile[t][ld] = v;
    }
    __syncthreads();

    const int d = tid >> 1;             // 0..127
    const int j0 = (tid & 1) * 32;      // t-half
    bf16 tmp[32];
#pragma unroll
    for (int j = 0; j < 32; j++) tmp[j] = tile[j0 + j][d];
    bf16* dst = Vt + ((size_t)bh * NHD + d) * NT + tt + j0;
#pragma unroll
    for (int j = 0; j < 4; j++)
        *(bf16x8*)(dst + j * 8) = *(const bf16x8*)(tmp + j * 8);
}

// ---------------------------------------------------------------------------
// Fused flash attention (non-causal, mask==0, S=1024, D=128).
// ---------------------------------------------------------------------------
__global__ __launch_bounds__(256, 2) void flash_k(
    const bf16* __restrict__ Qr,   // [(b*16+h)][t][128]
    const bf16* __restrict__ Kr,   // [(b*16+h)][t][128]
    const bf16* __restrict__ Vt,   // [(b*16+h)][d][1024]
    bf16* __restrict__ O) {        // [b*NT+t][ND], col h*128+d
    __shared__ char lds[81920];    // K: 2x16K @0, V: 2x16K @32768, P: 4x4K @65536

    const int tid = threadIdx.x;
    const int lane = tid & 63;
    const int w = tid >> 6;
    const int lm = lane & 15, lq = lane >> 4;
    const int lm7 = lm & 7;

    const int bh = blockIdx.y;
    const int q0 = blockIdx.x * 128;
    const bf16* Qb = Qr + (size_t)bh * NT * NHD;
    const bf16* Kb = Kr + (size_t)bh * NT * NHD;
    const bf16* Vb = Vt + (size_t)bh * NHD * NT;

    const int krow = tid >> 4;
    const int kc_s = (tid & 15);
    const int vrow = tid >> 3;
    const int vc_s = (tid & 7);

    bf16x8 q[2][4];
#pragma unroll
    for (int mi = 0; mi < 2; mi++)
#pragma unroll
        for (int ks = 0; ks < 4; ks++)
            q[mi][ks] = *(const bf16x8*)(Qb + (size_t)(q0 + w * 32 + mi * 16 + lm) * NHD
                                         + lq * 8 + ks * 32);

    f32x4 o0[8], o1[8];
#pragma unroll
    for (int i = 0; i < 8; i++) {
        f32x4 zz = {0.f, 0.f, 0.f, 0.f};
        o0[i] = zz; o1[i] = zz;
    }
    float m0[4], m1[4], l0[4], l1[4];
#pragma unroll
    for (int r = 0; r < 4; r++) {
        m0[r] = -3.0e38f; m1[r] = -3.0e38f; l0[r] = 0.f; l1[r] = 0.f;
    }

    char* Pb = lds + 65536 + w * 4096;
    const float kscal = 0.08838834764831845f * 1.4426950408889634f;

#pragma unroll
    for (int i = 0; i < 4; i++) {
        int row = i * 16 + krow;
        __builtin_amdgcn_global_load_lds(
            (gptr_t)(Kb + (size_t)row * NHD + (kc_s ^ (row & 7)) * 8),
            (lptr_t)(lds + i * 4096 + tid * 16), 16, 0, 0);
    }
#pragma unroll
    for (int i = 0; i < 4; i++) {
        int row = i * 32 + vrow;
        __builtin_amdgcn_global_load_lds(
            (gptr_t)(Vb + (size_t)row * NT + (vc_s ^ (row & 7)) * 8),
            (lptr_t)(lds + 32768 + i * 4096 + tid * 16), 16, 0, 0);
    }
    __syncthreads();

    for (int c = 0; c < 16; ++c) {
        char* Kl = lds + (c & 1) * 16384;
        char* Vl = lds + 32768 + (c & 1) * 16384;

        if (c < 15) {
            const int key1 = (c + 1) * 64;
            char* Kd = lds + ((c + 1) & 1) * 16384;
            char* Vd = lds + 32768 + ((c + 1) & 1) * 16384;
#pragma unroll
            for (int i = 0; i < 4; i++) {
                int row = i * 16 + krow;
                __builtin_amdgcn_global_load_lds(
                    (gptr_t)(Kb + (size_t)(key1 + row) * NHD + (kc_s ^ (row & 7)) * 8),
                    (lptr_t)(Kd + i * 4096 + tid * 16), 16, 0, 0);
            }
#pragma unroll
            for (int i = 0; i < 4; i++) {
                int row = i * 32 + vrow;
                __builtin_amdgcn_global_load_lds(
                    (gptr_t)(Vb + (size_t)row * NT + key1 + (vc_s ^ (row & 7)) * 8),
                    (lptr_t)(Vd + i * 4096 + tid * 16), 16, 0, 0);
            }
        }

        // ---- QK^T ----
        f32x4 s0[4], s1[4];
#pragma unroll
        for (int ni = 0; ni < 4; ni++) {
            f32x4 zz = {0.f, 0.f, 0.f, 0.f};
            s0[ni] = zz; s1[ni] = zz;
        }
        __builtin_amdgcn_s_setprio(1);
#pragma unroll
        for (int ni = 0; ni < 4; ni++) {
#pragma unroll
            for (int ks = 0; ks < 4; ks++) {
                bf16x8 kf = *(const bf16x8*)(Kl + (lm + 16 * ni) * 256
                                             + (((lq + 4 * ks) ^ lm7) << 4));
                s0[ni] = __builtin_amdgcn_mfma_f32_16x16x32_bf16(q[0][ks], kf, s0[ni], 0, 0, 0);
                s1[ni] = __builtin_amdgcn_mfma_f32_16x16x32_bf16(q[1][ks], kf, s1[ni], 0, 0, 0);
            }
        }
        __builtin_amdgcn_s_setprio(0);

#pragma unroll
        for (int ni = 0; ni < 4; ni++)
#pragma unroll
            for (int r = 0; r < 4; r++) {
                s0[ni][r] *= kscal;
                s1[ni][r] *= kscal;
            }

        float sc0[4], sc1[4];
#pragma unroll
        for (int r = 0; r < 4; r++) {
            float a0 = fmaxf(fmaxf(s0[0][r], s0[1][r]), fmaxf(s0[2][r], s0[3][r]));
            float a1 = fmaxf(fmaxf(s1[0][r], s1[1][r]), fmaxf(s1[2][r], s1[3][r]));
#pragma unroll
            for (int o = 1; o < 16; o <<= 1) {
                a0 = fmaxf(a0, __shfl_xor(a0, o));
                a1 = fmaxf(a1, __shfl_xor(a1, o));
            }
            float mn0 = fmaxf(m0[r], a0);
            float mn1 = fmaxf(m1[r], a1);
            sc0[r] = exp2f(m0[r] - mn0);
            sc1[r] = exp2f(m1[r] - mn1);
            m0[r] = mn0; m1[r] = mn1;

            float rs0 = 0.f, rs1 = 0.f;
#pragma unroll
            for (int ni = 0; ni < 4; ni++) {
                float p0 = exp2f(s0[ni][r] - mn0);
                float p1 = exp2f(s1[ni][r] - mn1);
                s0[ni][r] = p0; s1[ni][r] = p1;
                rs0 += p0; rs1 += p1;
            }
#pragma unroll
            for (int o = 1; o < 16; o <<= 1) {
                rs0 += __shfl_xor(rs0, o);
                rs1 += __shfl_xor(rs1, o);
            }
            l0[r] = l0[r] * sc0[r] + rs0;
            l1[r] = l1[r] * sc1[r] + rs1;
        }
#pragma unroll
        for (int ni = 0; ni < 8; ni++)
#pragma unroll
            for (int r = 0; r < 4; r++) {
                o0[ni][r] *= sc0[r];
                o1[ni][r] *= sc1[r];
            }

#pragma unroll
        for (int ni = 0; ni < 4; ni++)
#pragma unroll
            for (int r = 0; r < 4; r++) {
                int q_l0 = lq * 4 + r;
                int q_l1 = 16 + q_l0;
                int cw = (lm >> 3) + 2 * ni;
                *(bf16*)(Pb + q_l0 * 128 + ((cw ^ (q_l0 & 7)) << 4) + (lm7 << 1)) =
                    (bf16)s0[ni][r];
                *(bf16*)(Pb + q_l1 * 128 + ((cw ^ (q_l1 & 7)) << 4) + (lm7 << 1)) =
                    (bf16)s1[ni][r];
            }
        asm volatile("s_waitcnt lgkmcnt(0)" ::: "memory");
        __builtin_amdgcn_sched_barrier(0);

        __builtin_amdgcn_s_setprio(1);
#pragma unroll
        for (int ks = 0; ks < 2; ks++) {
            bf16x8 pa0 = *(const bf16x8*)(Pb + lm * 128 + (((lq + 4 * ks) ^ lm7) << 4));
            bf16x8 pa1 = *(const bf16x8*)(Pb + (lm + 16) * 128 + (((lq + 4 * ks) ^ lm7) << 4));
#pragma unroll
            for (int ni = 0; ni < 8; ni++) {
                bf16x8 vf = *(const bf16x8*)(Vl + (lm + 16 * ni) * 128
                                             + (((lq + 4 * ks) ^ lm7) << 4));
                o0[ni] = __builtin_amdgcn_mfma_f32_16x16x32_bf16(pa0, vf, o0[ni], 0, 0, 0);
                o1[ni] = __builtin_amdgcn_mfma_f32_16x16x32_bf16(pa1, vf, o1[ni], 0, 0, 0);
            }
        }
        __builtin_amdgcn_s_setprio(0);

        __syncthreads();
    }

    const int bb = bh >> 4, h = bh & 15;
    float rl0[4], rl1[4];
#pragma unroll
    for (int r = 0; r < 4; r++) { rl0[r] = 1.f / l0[r]; rl1[r] = 1.f / l1[r]; }
#pragma unroll
    for (int ni = 0; ni < 8; ni++) {
#pragma unroll
        for (int r = 0; r < 4; r++) {
            int col = h * 128 + lm + 16 * ni;
            long long r0 = (long long)bb * NT + q0 + w * 32 + lq * 4 + r;
            O[(r0) * ND + col]      = (bf16)(o0[ni][r] * rl0[r]);
            O[(r0 + 16) * ND + col] = (bf16)(o1[ni][r] * rl1[r]);
        }
    }
}

// ---------------------------------------------------------------------------
// 256xN pipelined GEMM (BK=64, counted-lgkmcnt, 2 barriers/K-tile).
//   NTILE=256 (MODE 0/6): 24 reads, 8 gloads/tile, LDS 128K.
//   NTILE=128 (MODE 2/5): 20 reads, 6 gloads/tile, LDS 96K; non-atomic
//   epilogues (exclusive tiles).
// MODE 0: C bf16 = alpha*acc          MODE 2: C fp32 += acc (exclusive)
// MODE 5: out[(b*NS+sel[m])*ND+n] += rw[m]*(acc+res)   (exclusive)
// MODE 6: dual-B (w1,w3): C bf16 = silu(acc1)*acc3
// ---------------------------------------------------------------------------
#define G256_SB() __builtin_amdgcn_sched_barrier(0)
#define G256_LGKM(n) do { asm volatile("s_waitcnt lgkmcnt(" #n ")" ::: "memory"); \
    __builtin_amdgcn_sched_barrier(0); } while (0)
#define G256_VMC(n) do { asm volatile("s_waitcnt vmcnt(" #n ")" ::: "memory"); \
    __builtin_amdgcn_sched_barrier(0); } while (0)

#define MFMA_Q(mlo, nlo) do { \
    __builtin_amdgcn_s_setprio(1); \
    _Pragma("unroll") \
    for (int _ks = 0; _ks < 2; _ks++) \
    _Pragma("unroll") \
    for (int _mi = 0; _mi < 4; _mi++) \
    _Pragma("unroll") \
    for (int _ni = 0; _ni < 2; _ni++) \
        acc[(mlo) + _mi][(nlo) + _ni] = __builtin_amdgcn_mfma_f32_16x16x32_bf16( \
            a[(mlo) + _mi][_ks], b[(nlo) + _ni][_ks], acc[(mlo) + _mi][(nlo) + _ni], \
            0, 0, 0); \
    __builtin_amdgcn_s_setprio(0); \
} while (0)

template <int MODE>
__global__ __launch_bounds__(512, 2) void gemm256(
    const bf16* __restrict__ A, int lda,
    const bf16* __restrict__ Bt, int ldb,
    void* __restrict__ Cv, int ldc,
    int K, float alpha,
    const bf16* __restrict__ Bt2,
    const float* __restrict__ res, const int* __restrict__ selp,
    const float* __restrict__ rwp, float* __restrict__ outp) {

    constexpr bool DUALB = (MODE == 6);
    constexpr bool N128  = (MODE == 2 || MODE == 5);
    constexpr bool NI4   = !N128;                    // 4 B-frag pairs
    constexpr int  BBUF  = N128 ? 16384 : 32768;     // B bytes per buffer
    constexpr int  BUFS  = 32768 + BBUF;             // per-buffer bytes
    constexpr int  bw    = (DUALB || N128) ? 32 : 64;   // cols per wave
    constexpr int  bStep2 = DUALB ? 16384 : 4096;    // ni-pair 1 byte offset
    constexpr int  NIE   = (DUALB || N128) ? 2 : 4;  // epilogue ni count
    __shared__ char smem[2 * BUFS];

    const int tid = threadIdx.x;
    const int lane = tid & 63;
    const int wid = tid >> 6;
    const int wm = wid >> 2, wn = wid & 3;     // 2 x 4 waves
    const int lm = lane & 15, lq = lane >> 4;

    // 2D XCD mapping: xcd quadrant (2M x 4N), 8 x (nx/4) rect inside, M-first.
    // Requires ny==16, nx%4==0.
    const int nx = gridDim.x;
    const int orig = blockIdx.y * nx + blockIdx.x;
    const int xcd = orig & 7;
    const int r_ = orig >> 3;
    const int mi_ = r_ & 7, ni_ = r_ >> 3;
    const int nT = (DUALB || N128) ? 128 : 256;
    const int m0 = ((xcd >> 2) * 8 + mi_) * 256;
    const int n0 = ((xcd & 3) * (nx >> 2) + ni_) * nT;
    const long long kz = (long long)blockIdx.z * K;

    // staging: thread stages 16B chunk; LDS linear, global source pre-swizzled
    const int srow = tid >> 3;                 // [0,64)
    const int skc = ((tid & 7) ^ (srow & 7)) * 8;
    const long long stA = (long long)64 * lda;
    const long long stB = (long long)64 * ldb;
    const bf16* gA = A + (long long)(m0 + srow) * lda + kz + skc;
    const bf16* gB0 = Bt + (long long)(n0 + srow) * ldb + kz + skc;
    const bf16* gB2 = DUALB ? Bt2 + (long long)(n0 + srow) * ldb + kz + skc
                            : gB0 + 2 * stB;

    char* sm = (char*)smem;
    const int sdst = tid * 16;

    auto stage = [&](int c, int t) {
        char* lA = sm + c * BUFS + sdst;
        long long ko = (long long)t * 64;
#pragma unroll
        for (int i = 0; i < 4; i++)
            __builtin_amdgcn_global_load_lds((gptr_t)(gA + i * stA + ko),
                                             (lptr_t)(lA + i * 8192), 16, 0, 0);
        char* lB = sm + c * BUFS + 32768 + sdst;
        __builtin_amdgcn_global_load_lds((gptr_t)(gB0 + ko), (lptr_t)lB, 16, 0, 0);
        __builtin_amdgcn_global_load_lds((gptr_t)(gB0 + stB + ko),
                                         (lptr_t)(lB + 8192), 16, 0, 0);
        if constexpr (NI4) {
            __builtin_amdgcn_global_load_lds((gptr_t)(gB2 + ko),
                                             (lptr_t)(lB + 16384), 16, 0, 0);
            __builtin_amdgcn_global_load_lds((gptr_t)(gB2 + stB + ko),
                                             (lptr_t)(lB + 24576), 16, 0, 0);
        }
    };

    // frag read offsets: row*128 + ((ks*4+lq) ^ (lm&7))*16 ; ks=1 is ^64
    const int aoff = (wm * 128 + lm) * 128 + ((lq ^ (lm & 7)) << 4);
    const int boff = (wn * bw + lm) * 128 + ((lq ^ (lm & 7)) << 4);

    f32x4 acc[8][4];
#pragma unroll
    for (int i = 0; i < 8; i++)
#pragma unroll
        for (int j = 0; j < 4; j++) {
            f32x4 zz = {0.f, 0.f, 0.f, 0.f};
            acc[i][j] = zz;
        }
    bf16x8 a[8][2], b[4][2];

    auto ldA4 = [&](char* bA, int lo) {
#pragma unroll
        for (int mi2 = 0; mi2 < 4; mi2++) {
            a[lo + mi2][0] = *(const bf16x8*)(bA + aoff + (lo + mi2) * 2048);
            a[lo + mi2][1] = *(const bf16x8*)(bA + (aoff ^ 64) + (lo + mi2) * 2048);
        }
    };
    auto ldB2 = [&](char* bB, int lo) {
#pragma unroll
        for (int ni2 = 0; ni2 < 2; ni2++) {
            int ix = lo + ni2;
            int o = boff + (ix & 1) * 2048 + (ix >> 1) * bStep2;
            b[ix][0] = *(const bf16x8*)(bB + o);
            b[ix][1] = *(const bf16x8*)(bB + (o ^ 64));
        }
    };

    const int NTk = K >> 6;

    // prologue: stage tile0 -> buf0, tile1 -> buf1; wait tile0
    stage(0, 0);
    stage(1, 1);
    if constexpr (NI4) { G256_VMC(8); } else { G256_VMC(6); }
    __builtin_amdgcn_s_barrier();
    G256_SB();

    for (int t = 0; t < NTk; ++t) {
        const int c = t & 1;
        char* bA = sm + c * BUFS;
        char* bB = bA + 32768;

        // issue all frag reads; group order pinned (counts depend on it)
        ldA4(bA, 0);
        ldB2(bB, 0);           // group1: 12 reads
        G256_SB();
        if constexpr (NI4) {
            ldB2(bB, 2);       // group2: 4 reads
            G256_SB();
        }
        ldA4(bA, 4);           // group3: 8 reads
        G256_SB();

        if constexpr (NI4) { G256_LGKM(12); } else { G256_LGKM(8); }
        MFMA_Q(0, 0);
        if constexpr (NI4) {
            G256_LGKM(8);
            MFMA_Q(0, 2);
        }
        G256_LGKM(0);                        // all reads of buf c done
        __builtin_amdgcn_s_barrier();        // release buf c
        G256_SB();
        const bool more = (t + 2 < NTk);
        if (more) stage(c, t + 2);           // overwrite buf c with t+2
        G256_SB();
        MFMA_Q(4, 0);                        // overlaps staging
        if constexpr (NI4) MFMA_Q(4, 2);
        if (more) {
            if constexpr (NI4) { G256_VMC(8); } else { G256_VMC(6); }
        } else {
            G256_VMC(0);
        }
        __builtin_amdgcn_s_barrier();        // buf c^1 (tile t+1) visible
        G256_SB();
    }

    if constexpr (MODE == 6) {
        bf16* C = (bf16*)Cv;
#pragma unroll
        for (int mi = 0; mi < 8; mi++) {
#pragma unroll
            for (int ni = 0; ni < 2; ni++) {
                const int row = m0 + wm * 128 + mi * 16 + lq * 4;
                const int col = n0 + wn * 32 + ni * 16 + lm;
#pragma unroll
                for (int r = 0; r < 4; r++) {
                    float v1 = acc[mi][ni][r];
                    float v3 = acc[mi][ni + 2][r];
                    C[(long long)(row + r) * ldc + col] =
                        (bf16)((v1 / (1.f + __expf(-v1))) * v3);
                }
            }
        }
    } else {
#pragma unroll
        for (int mi = 0; mi < 8; mi++) {
#pragma unroll
            for (int ni = 0; ni < NIE; ni++) {
                const int row = m0 + wm * 128 + mi * 16 + lq * 4;
                const int col = n0 + wn * bw + ni * 16 + lm;
#pragma unroll
                for (int r = 0; r < 4; r++) {
                    float v = alpha * acc[mi][ni][r];
                    long long rr = row + r;
                    if constexpr (MODE == 0) {
                        bf16* C = (bf16*)Cv;
                        C[rr * ldc + col] = (bf16)v;
                    } else if constexpr (MODE == 2) {
                        float* C = (float*)Cv;
                        C[rr * ldc + col] += v;       // exclusive tile
                    } else {   // MODE 5
                        int bb2 = (int)(rr >> 10);
                        int s = selp[rr];
                        float add = rwp[rr] * (v + res[rr * (long long)ND + col]);
                        outp[((long long)bb2 * NS + s) * ND + col] += add;  // exclusive
                    }
                }
            }
        }
    }
}

// ---------------------------------------------------------------------------
extern "C" void kernel_launch(void* const* d_in, const int* in_sizes, int n_in,
                              void* d_out, int out_size, void* d_ws, size_t ws_size,
                              hipStream_t stream) {
    const float* x  = (const float*)d_in[0];
    const float* fr = (const float*)d_in[2];
    const float* wr = (const float*)d_in[3];
    const float* g1 = (const float*)d_in[4];
    const float* wq = (const float*)d_in[5];
    const float* wk = (const float*)d_in[6];
    const float* wv = (const float*)d_in[7];
    const float* wo = (const float*)d_in[8];
    const float* g2 = (const float*)d_in[9];
    const float* w1 = (const float*)d_in[10];
    const float* w3 = (const float*)d_in[11];
    const float* w2 = (const float*)d_in[12];
    float* out = (float*)d_out;

    char* ws = (char*)d_ws;
    size_t off = 0;
    auto take = [&](size_t bytes) -> char* {
        char* p = ws + off;
        off += (bytes + 255) & ~(size_t)255;
        return p;
    };
    int*   sel    = (int*)take((size_t)NB * NT * 4);
    float* rw     = (float*)take((size_t)NB * NT * 4);
    float* logits = (float*)take((size_t)NB * NS * 4);
    float* xf     = (float*)take((size_t)NB * NT * ND * 4);
    bf16*  hbuf   = (bf16*)take((size_t)NB * NT * ND * 2);
    bf16*  wqkv_t = (bf16*)take((size_t)3 * ND * ND * 2);
    bf16*  wo_t   = (bf16*)take((size_t)ND * ND * 2);
    bf16*  Obuf   = (bf16*)take((size_t)NB * NT * ND * 2);
    char* xr = ws + off;
    // attention-phase overlay
    bf16* QKV = (bf16*)xr;                               // [4096][6144]
    bf16* Qr  = QKV + (size_t)NB * NT * 3 * ND;
    bf16* Kr  = Qr + (size_t)NB * NT * ND;
    bf16* Vt  = Kr + (size_t)NB * NT * ND;
    // FFN-phase overlay (attention data dead by then)
    bf16* w1_t  = (bf16*)xr;
    bf16* w3_t  = w1_t + (size_t)ND * NF;
    bf16* w2_t  = w3_t + (size_t)ND * NF;
    bf16* inter = w2_t + (size_t)ND * NF;

    // router + out = x copy fused (x streamed once)
    router_copy_k<<<NB * NS, 256, 0, stream>>>(x, wr, logits, (float4*)out);
    topk_k<<<NB, 1024, 0, stream>>>(logits, sel, rw);
    // gather + rmsnorm #1 fused (writes xf residual + normalized hbuf)
    gather_rms_k<<<NB * NT, 256, 0, stream>>>(x, sel, g1, xf, hbuf);

    dim3 tg(ND / 32, ND / 32);
    transpose_to_bf16<<<tg, 256, 0, stream>>>(wq, wqkv_t, ND, ND);
    transpose_to_bf16<<<tg, 256, 0, stream>>>(wk, wqkv_t + (size_t)ND * ND, ND, ND);
    transpose_to_bf16<<<tg, 256, 0, stream>>>(wv, wqkv_t + (size_t)2 * ND * ND, ND, ND);
    transpose_to_bf16<<<tg, 256, 0, stream>>>(wo, wo_t, ND, ND);

    // fused QKV: [4096 x 2048] x [6144 x 2048]^T -> [4096][6144]
    gemm256<0><<<dim3(3 * ND / 256, NB * NT / 256, 1), 512, 0, stream>>>(
        hbuf, ND, wqkv_t, ND, QKV, 3 * ND, ND, 1.0f,
        nullptr, nullptr, nullptr, nullptr, nullptr);

    rope_qk_k<<<(NB * NT * NH * 64) / 256, 256, 0, stream>>>(QKV, fr, Qr, Kr);
    vtr_k<<<dim3(NT / 64, NB * NH), 256, 0, stream>>>(QKV, Vt);

    // fused flash attention
    flash_k<<<dim3(NT / 128, NB * NH), 256, 0, stream>>>(Qr, Kr, Vt, Obuf);

    // WO: 128-N tiles, single-z, non-atomic += into xf residual
    gemm256<2><<<dim3(ND / 128, NB * NT / 256, 1), 512, 0, stream>>>(
        Obuf, ND, wo_t, ND, xf, ND, ND, 1.0f,
        nullptr, nullptr, nullptr, nullptr, nullptr);

    rmsnorm_k<<<NB * NT, 256, 0, stream>>>(xf, g2, hbuf);

    transpose_to_bf16<<<dim3(NF / 32, ND / 32), 256, 0, stream>>>(w1, w1_t, ND, NF);
    transpose_to_bf16<<<dim3(NF / 32, ND / 32), 256, 0, stream>>>(w3, w3_t, ND, NF);
    transpose_to_bf16<<<dim3(ND / 32, NF / 32), 256, 0, stream>>>(w2, w2_t, NF, ND);

    // fused FFN up: inter = silu(h.w1) * (h.w3)
    gemm256<6><<<dim3(NF / 128, NB * NT / 256, 1), 512, 0, stream>>>(
        hbuf, ND, w1_t, ND, inter, NF, ND, 1.0f,
        w3_t, nullptr, nullptr, nullptr, nullptr);

    // w2 + scatter-add: 128-N tiles, single-z, non-atomic (tiles exclusive)
    gemm256<5><<<dim3(ND / 128, NB * NT / 256, 1), 512, 0, stream>>>(
        inter, NF, w2_t, NF, nullptr, ND, NF, 1.0f,
        nullptr, xf, sel, rw, out);
}